// Round 9
// baseline (290.096 us; speedup 1.0000x reference)
//
#include <hip/hip_runtime.h>
#include <hip/hip_bf16.h>

typedef unsigned short u16;
typedef float f32x4 __attribute__((ext_vector_type(4)));
typedef __bf16 bf16x8 __attribute__((ext_vector_type(8)));
typedef __bf16 bf16x4 __attribute__((ext_vector_type(4)));
typedef unsigned short su8v __attribute__((ext_vector_type(8)));
typedef unsigned short su4v __attribute__((ext_vector_type(4)));
typedef short s16x4 __attribute__((ext_vector_type(4)));

#define BB 8
#define NHD 8
#define DD 128
#define NN 1024
#define DIM 1024
#define H3 3072
#define MM 8192
// scale * log2(e), folded into Q weights so softmax is exp2(raw dot)
#define QSC (0.08838834764831845f * 1.4426950408889634f)

__constant__ int   d_IDX[16] = {0,1,2,3, 1,0,3,2, 2,3,0,1, 3,2,1,0};
__constant__ float d_SGN[16] = {1.f,-1.f,-1.f,-1.f, 1.f,1.f,1.f,-1.f,
                                1.f,-1.f,1.f,1.f,  1.f,1.f,-1.f,1.f};

__device__ __forceinline__ f32x4 mfma16(su8v a, su8v b, f32x4 c) {
  return __builtin_amdgcn_mfma_f32_16x16x32_bf16(
      __builtin_bit_cast(bf16x8, a), __builtin_bit_cast(bf16x8, b), c, 0, 0, 0);
}
// 16x16x16 bf16 MFMA (K=16): A/B are 4 bf16 (2 VGPRs). Used for PV so the
// QK^T output registers feed PV directly (lane: m=l16, k=quad*4+e).
__device__ __forceinline__ f32x4 mfma16h(su4v a, su4v b, f32x4 c) {
#if __has_builtin(__builtin_amdgcn_mfma_f32_16x16x16_bf16)
  return __builtin_amdgcn_mfma_f32_16x16x16_bf16(
      __builtin_bit_cast(bf16x4, a), __builtin_bit_cast(bf16x4, b), c, 0, 0, 0);
#elif __has_builtin(__builtin_amdgcn_mfma_f32_16x16x16bf16_1k)
  return __builtin_amdgcn_mfma_f32_16x16x16bf16_1k(
      __builtin_bit_cast(s16x4, a), __builtin_bit_cast(s16x4, b), c, 0, 0, 0);
#else
  f32x4 d = c;
  asm("v_mfma_f32_16x16x16_bf16 %0, %1, %2, %0" : "+v"(d) : "v"(a), "v"(b));
  return d;
#endif
}
__device__ __forceinline__ u16 f2b(float f) {  // RNE
  unsigned int u = __builtin_bit_cast(unsigned int, f);
  u += 0x7fffu + ((u >> 16) & 1u);
  return (u16)(u >> 16);
}
__device__ __forceinline__ float b2f(u16 v) {
  unsigned int u = ((unsigned int)v) << 16;
  return __builtin_bit_cast(float, u);
}
typedef const __attribute__((address_space(1))) unsigned int* gas_t;
typedef __attribute__((address_space(3))) unsigned int* las_t;
__device__ __forceinline__ void gll16(const u16* g, u16* l) {
  __builtin_amdgcn_global_load_lds((gas_t)g, (las_t)l, 16, 0, 0);
}

// ---------------------------------------------------------------------------
// prep_weff: effective weights [out_row][in_col] bf16; Q-rows pre-scaled by QSC
// ---------------------------------------------------------------------------
__global__ __launch_bounds__(256) void prep_weff(
    const float* __restrict__ wqkv, const float* __restrict__ wproj,
    u16* __restrict__ weffQ, u16* __restrict__ weffP) {
  int tid = blockIdx.x * 256 + threadIdx.x;
  int stride = gridDim.x * 256;
  for (int i = tid; i < H3 * DIM; i += stride) {
    int row = i >> 10, col = i & 1023;
    int q = row / 768, o = row - q * 768;
    int p = col >> 8, c = col & 255;
    float v = d_SGN[q * 4 + p] * wqkv[(d_IDX[q * 4 + p] * 768 + o) * 256 + c];
    if (o < 256) v *= QSC;  // Q rows
    weffQ[i] = f2b(v);
  }
  for (int i = tid; i < DIM * DIM; i += stride) {
    int row = i >> 10, col = i & 1023;
    int q = row >> 8, o = row & 255;
    int p = col >> 8, c = col & 255;
    weffP[i] = f2b(d_SGN[q * 4 + p] * wproj[(d_IDX[q * 4 + p] * 256 + o) * 256 + c]);
  }
}

// ---------------------------------------------------------------------------
// prep_x: x (B,Cc,4,N) fp32 -> Ax bf16 [8192 (b,n)][1024 (p,c)].
// LDS transpose, layout T[n][pc] stride 264 u16 (16B-aligned su8v reads).
// ---------------------------------------------------------------------------
__global__ __launch_bounds__(256) void prep_x(
    const float* __restrict__ x, u16* __restrict__ Ax) {
  __shared__ u16 T[64 * 264];  // [n][pc], stride 264
  int blk = blockIdx.x;
  int nc = blk & 15;
  int cc = (blk >> 4) & 3;
  int b = blk >> 6;
  int n0 = nc * 64, c0 = cc * 64;
  int tid = threadIdx.x;
  int nseg = tid & 15, rq = tid >> 4;  // rq 0..15
#pragma unroll
  for (int pass = 0; pass < 16; ++pass) {
    int rr = pass * 16 + rq;  // pc local 0..255: p = rr>>6, c = rr&63
    int p = rr >> 6, c = rr & 63;
    float4 f = *(const float4*)(x + (((size_t)(b * 256 + c0 + c)) * 4 + p) * 1024 +
                                n0 + nseg * 4);
    T[(nseg * 4 + 0) * 264 + rr] = f2b(f.x);
    T[(nseg * 4 + 1) * 264 + rr] = f2b(f.y);
    T[(nseg * 4 + 2) * 264 + rr] = f2b(f.z);
    T[(nseg * 4 + 3) * 264 + rr] = f2b(f.w);
  }
  __syncthreads();
  int nl = tid >> 5, lc = tid & 31;
#pragma unroll
  for (int pass = 0; pass < 8; ++pass) {
    int n = pass * 8 + nl;
    su8v v = *(const su8v*)(&T[n * 264 + lc * 8]);
    int pcl = lc * 8;
    *(su8v*)(Ax + (size_t)(b * 1024 + n0 + n) * 1024 + (pcl >> 6) * 256 + c0 +
             (pcl & 63)) = v;
  }
}

// ---------------------------------------------------------------------------
// 8-wave GEMM core, ONE barrier per K-tile + counted vmcnt, free-running
// waves. Tile BM x BN (BM+BN == 384), BK=64, 512 threads = 8 waves of 64x64.
// 3-slot LDS ring; loads for 2 future tiles stay in flight across barriers.
// LDS rows 64 u16 = 8 x 16B blocks, XOR-swizzled (blk ^= row&7); global
// source pre-swizzled identically so gll's linear LDS write lands right.
// ---------------------------------------------------------------------------
template <int BM, int BN>
__device__ __forceinline__ void gemm_core8(
    const u16* __restrict__ Ag, const u16* __restrict__ Bg,
    u16* As, u16* Bs, int tid, f32x4 (&acc)[4][4]) {
  constexpr int WN = BN / 64;
  constexpr int AC = BM / 64;
  constexpr int BC = BN / 64;
  constexpr int NT = 16;  // K = 1024 / BK(64)
  int w = tid >> 6, lane = tid & 63, l16 = lane & 15, quad = lane >> 4;
  int wm = w / WN, wn = w % WN;
  int x7 = l16 & 7;
  int srow = lane >> 3;
  int sblk = (lane & 7) ^ srow;

  auto STAGE_A = [&](int tt, int bs) {
#pragma unroll
    for (int c = 0; c < AC; ++c) {
      int r0 = c * 64 + w * 8;
      gll16(Ag + (size_t)(r0 + srow) * 1024 + tt * 64 + sblk * 8,
            As + (size_t)bs * (BM * 64) + r0 * 64);
    }
  };
  auto STAGE_B = [&](int tt, int bs) {
#pragma unroll
    for (int c = 0; c < BC; ++c) {
      int r0 = c * 64 + w * 8;
      gll16(Bg + (size_t)(r0 + srow) * 1024 + tt * 64 + sblk * 8,
            Bs + (size_t)bs * (BN * 64) + r0 * 64);
    }
  };

  STAGE_A(0, 0); STAGE_B(0, 0);
  STAGE_A(1, 1); STAGE_B(1, 1);
  asm volatile("s_waitcnt vmcnt(6)" ::: "memory");
  __builtin_amdgcn_s_barrier();

  int cur = 0, nxt = 1, stg = 2;
  for (int t = 0; t < NT; ++t) {
    const u16* At = As + (size_t)cur * (BM * 64);
    const u16* Bt = Bs + (size_t)cur * (BN * 64);
#pragma unroll
    for (int kk = 0; kk < 2; ++kk) {
      su8v af[4], bf[4];
#pragma unroll
      for (int i = 0; i < 4; ++i)
        af[i] = *(const su8v*)(At + (wm * 64 + i * 16 + l16) * 64 +
                               ((kk * 4 + quad) ^ x7) * 8);
#pragma unroll
      for (int j = 0; j < 4; ++j)
        bf[j] = *(const su8v*)(Bt + (wn * 64 + j * 16 + l16) * 64 +
                               ((kk * 4 + quad) ^ x7) * 8);
      if (t + 2 < NT) {
        if (kk == 0) STAGE_A(t + 2, stg);
        else         STAGE_B(t + 2, stg);
      }
      __builtin_amdgcn_s_setprio(1);
#pragma unroll
      for (int i = 0; i < 4; ++i)
#pragma unroll
        for (int j = 0; j < 4; ++j)
          acc[i][j] = mfma16(af[i], bf[j], acc[i][j]);
      __builtin_amdgcn_s_setprio(0);
    }
    if (t < NT - 2)       asm volatile("s_waitcnt vmcnt(6)" ::: "memory");
    else if (t == NT - 2) asm volatile("s_waitcnt vmcnt(0)" ::: "memory");
    asm volatile("" ::: "memory");
    __builtin_amdgcn_s_barrier();
    asm volatile("" ::: "memory");
    int tmp = cur; cur = nxt; nxt = stg; stg = tmp;
  }
}

// ---------------------------------------------------------------------------
// QKV GEMM: tile = 256 (bn) x 128 (chan). Grid 32x24 = 768 blocks.
// V store: halves of each 8-key group swapped when (d>>3)&1 (npos^4) so
// attn's Vt b64 reads can spread the l16-bit3 into the byte-half -> LDS
// bank-phase conflict-free (see attn_mfma comment).
// ---------------------------------------------------------------------------
__global__ __launch_bounds__(512, 2) void gemm_qkv_mfma(
    const u16* __restrict__ Ax, const u16* __restrict__ weffQ,
    const float* __restrict__ bqkv,
    u16* __restrict__ Qb, u16* __restrict__ Kb, u16* __restrict__ VbT) {
  __shared__ u16 smem[3 * 384 * 64];  // 144 KB: 3-slot ring, A tile + B tile
  int bn0 = blockIdx.x * 256;
  int col0 = blockIdx.y * 128;
  int q = col0 / 768;
  int off = col0 - q * 768;
  int sel = off >> 8;  // 0=Q 1=K 2=V (uniform)
  int head = (q * 256 + (off & 255)) >> 7;
  int tid = threadIdx.x;
  int w = tid >> 6, lane = tid & 63, l16 = lane & 15, quad = lane >> 4;
  f32x4 acc[4][4];
#pragma unroll
  for (int i = 0; i < 4; ++i)
#pragma unroll
    for (int j = 0; j < 4; ++j) acc[i][j] = (f32x4){0.f, 0.f, 0.f, 0.f};

  if (sel == 2) {
    // ---- V: m=bn (256), n=chan (128) ----
    gemm_core8<256, 128>(Ax + (size_t)bn0 * 1024, weffQ + (size_t)col0 * 1024,
                         smem, smem + 3 * 256 * 64, tid, acc);
    int wm = w >> 1, wn = w & 1;
#pragma unroll
    for (int j = 0; j < 4; ++j) {
      int dl = wn * 64 + j * 16 + l16;
      float bias = bqkv[col0 + dl];
      int hswap = ((dl >> 3) & 1) << 2;  // half-swap per d-octet parity
#pragma unroll
      for (int i = 0; i < 4; ++i) {
        int m = bn0 + wm * 64 + i * 16 + quad * 4;
        int b = m >> 10, npos = m & 1023;
        int bh = b * NHD + head;
        su4v pk;
#pragma unroll
        for (int r = 0; r < 4; ++r) pk[r] = f2b(acc[i][j][r] + bias);
        *(su4v*)(VbT + ((size_t)bh * DD + dl) * NN + (npos ^ hswap)) = pk;
      }
    }
  } else {
    // ---- Q/K: m=chan (128), n=bn (256) ----
    gemm_core8<128, 256>(weffQ + (size_t)col0 * 1024, Ax + (size_t)bn0 * 1024,
                         smem, smem + 3 * 128 * 64, tid, acc);
    int wm = w >> 2, wn = w & 3;
    u16* dst = (sel == 0) ? Qb : Kb;
    float sc = (sel == 0) ? (float)QSC : 1.0f;
#pragma unroll
    for (int i = 0; i < 4; ++i) {
      int dbase = wm * 64 + i * 16 + quad * 4;
      float4 b4 = *(const float4*)(bqkv + col0 + dbase);
#pragma unroll
      for (int j = 0; j < 4; ++j) {
        int n = bn0 + wn * 64 + j * 16 + l16;
        int b = n >> 10, npos = n & 1023;
        int bh = b * NHD + head;
        su4v pk;
        pk[0] = f2b(acc[i][j][0] + b4.x * sc);
        pk[1] = f2b(acc[i][j][1] + b4.y * sc);
        pk[2] = f2b(acc[i][j][2] + b4.z * sc);
        pk[3] = f2b(acc[i][j][3] + b4.w * sc);
        *(su4v*)(dst + ((size_t)bh * NN + npos) * DD + dbase) = pk;
      }
    }
  }
}

// ---------------------------------------------------------------------------
// Flash attention, split-K x2: 1024 blocks = half(2) x qt(8) x bh(64).
// 128 q x 512 keys per block. Single-buffered K/V (32 KB). In-register P.
// Bank-conflict elimination (round-8: 192 cyc/wave-kt, all phase conflicts
// between lanes l16 and l16+8):
//  - Ks: 4-bit XOR swizzle (16 blocks/row): slot = blk ^ (key&15). 16-lane
//    b128 phases hit 16 distinct 4-bank groups.
//  - Vt: rows have only 8 blocks, so the l16-bit3 goes into the byte-HALF:
//    V is stored globally with 4-key halves swapped when (d>>3)&1 (qkv
//    epilogue npos^4); read half = (quad&1)^(l16>>3). Keys retrieved are
//    provably j*16+quad*4+e in order.
// Row-sum ls via ones-vector MFMA (matrix pipe 30% busy vs VALU 46%):
// D[q][*] = sum_k P[q][k]; replaces 32 VALU adds/kt + shfl reduce, and the
// P-truncation bias now cancels exactly between O and l.
// No launch_bounds min-waves (rounds 6/7: any cap below natural ~112-120
// regs causes scratch spill collapse).
// ---------------------------------------------------------------------------
__global__ __launch_bounds__(256) void attn_mfma(
    const u16* __restrict__ Qb, const u16* __restrict__ Kb,
    const u16* __restrict__ VbT, u16* __restrict__ OP,
    float* __restrict__ LS) {
  __shared__ u16 Ks[64 * 128];  // 16 KB, 4-bit xor-swizzled 16B blocks
  __shared__ u16 Vt[128 * 64];  // 16 KB, 3-bit xor + half-swap
  int blk = blockIdx.x;
  int bh = blk & 63;  // low bits -> blk%8 == bh%8 (same XCD for K/V L2 reuse)
  int rest = blk >> 6;
  int qt = rest & 7;
  int half = rest >> 3;
  int n0 = qt * 128;
  int tid = threadIdx.x;
  int w = tid >> 6, lane = tid & 63, l16 = lane & 15, quad = lane >> 4;
  const u16* Qg = Qb + ((size_t)bh * NN + n0) * DD;
  const u16* Kg = Kb + (size_t)bh * NN * DD;
  const u16* Vg = VbT + (size_t)bh * DD * NN;
  int x7 = l16 & 7;
  int vhalf = ((quad & 1) ^ (l16 >> 3)) * 4;  // Vt byte-half select (u16)

  su8v qreg[2][4];  // B-fragment: n=q (l16), k=d
#pragma unroll
  for (int mi = 0; mi < 2; ++mi)
#pragma unroll
    for (int ch = 0; ch < 4; ++ch)
      qreg[mi][ch] = *(const su8v*)(Qg + (size_t)(w * 32 + mi * 16 + l16) * DD +
                                    ch * 32 + quad * 8);

  su4v ones;
  ones[0] = 0x3F80; ones[1] = 0x3F80; ones[2] = 0x3F80; ones[3] = 0x3F80;
  f32x4 accL[2];
  accL[0] = (f32x4){0.f, 0.f, 0.f, 0.f};
  accL[1] = (f32x4){0.f, 0.f, 0.f, 0.f};
  f32x4 accO[2][8];
#pragma unroll
  for (int mi = 0; mi < 2; ++mi)
#pragma unroll
    for (int dt = 0; dt < 8; ++dt) accO[mi][dt] = (f32x4){0.f, 0.f, 0.f, 0.f};

  for (int kt = 0; kt < 8; ++kt) {
    int c0 = half * 512 + kt * 64;
    __syncthreads();
#pragma unroll
    for (int t = 0; t < 4; ++t) {
      int ci = w * 4 + t;
      // K: rows of 256B = 16 x 16B blocks; 4-bit swizzle blk ^ (key&15)
      int krow = ci * 4 + (lane >> 4);
      int kblk = (lane & 15) ^ (krow & 15);
      gll16(Kg + (size_t)(c0 + krow) * DD + kblk * 8, Ks + ci * 512);
      // V^T: rows of 128B = 8 x 16B blocks; 3-bit xor (halves pre-swapped
      // in global storage by gemm_qkv for (d>>3)&1)
      int dv = ci * 8 + (lane >> 3);
      int vblk = (lane & 7) ^ (dv & 7);
      gll16(Vg + (size_t)dv * NN + c0 + vblk * 8, Vt + ci * 512);
    }
    __syncthreads();

    // fused per-16-key-slice: QK^T -> exp2/pack -> PV + ones-MFMA row-sum
#pragma unroll
    for (int j = 0; j < 4; ++j) {
      f32x4 s0 = (f32x4){0.f, 0.f, 0.f, 0.f};
      f32x4 s1 = (f32x4){0.f, 0.f, 0.f, 0.f};
#pragma unroll
      for (int ch = 0; ch < 4; ++ch) {
        su8v kf = *(const su8v*)(Ks + (j * 16 + l16) * 128 +
                                 (((ch * 4 + quad) ^ l16) * 8));
        s0 = mfma16(kf, qreg[0][ch], s0);
        s1 = mfma16(kf, qreg[1][ch], s1);
      }
      su4v p0, p1;
#pragma unroll
      for (int r = 0; r < 4; ++r) {
        float pa = __builtin_exp2f(s0[r]);
        p0[r] = (u16)(__builtin_bit_cast(unsigned int, pa) >> 16);
        float pb = __builtin_exp2f(s1[r]);
        p1[r] = (u16)(__builtin_bit_cast(unsigned int, pb) >> 16);
      }
      accL[0] = mfma16h(p0, ones, accL[0]);
      accL[1] = mfma16h(p1, ones, accL[1]);
#pragma unroll
      for (int dt = 0; dt < 8; ++dt) {
        su4v vf = *(const su4v*)(Vt + (dt * 16 + l16) * 64 +
                                 ((((j * 2 + (quad >> 1)) ^ x7) << 3) + vhalf));
        accO[0][dt] = mfma16h(p0, vf, accO[0][dt]);
        accO[1][dt] = mfma16h(p1, vf, accO[1][dt]);
      }
    }
  }

  size_t hb = (size_t)(half * 64 + bh);
  // accL: lane (l16,quad) holds row-sums for q rows quad*4+r (all l16 equal)
  if (l16 == 0) {
#pragma unroll
    for (int mi = 0; mi < 2; ++mi)
      *(float4*)(&LS[hb * NN + n0 + w * 32 + mi * 16 + quad * 4]) =
          *(float4*)(&accL[mi]);
  }
  // store unnormalized O partial (bf16)
#pragma unroll
  for (int mi = 0; mi < 2; ++mi)
#pragma unroll
    for (int r = 0; r < 4; ++r) {
      int row = w * 32 + mi * 16 + quad * 4 + r;
      size_t base = (hb * NN + n0 + row) * DD;
#pragma unroll
      for (int dt = 0; dt < 8; ++dt)
        OP[base + dt * 16 + l16] = f2b(accO[mi][dt][r]);
    }
}

// ---------------------------------------------------------------------------
// merge: AO[b,n][head*128+d] = (O0 + O1) / (l0 + l1)
// ---------------------------------------------------------------------------
__global__ __launch_bounds__(256) void attn_merge(
    const u16* __restrict__ OP, const float* __restrict__ LS,
    u16* __restrict__ AO) {
  size_t idx = (size_t)blockIdx.x * 256 + threadIdx.x;  // 4-elem chunk id
  size_t e = idx * 4;
  int d = (int)(e & 127);
  size_t bhn = e >> 7;  // bh*1024 + n
  su4v a = *(const su4v*)(OP + bhn * DD + d);
  su4v b = *(const su4v*)(OP + (size_t)64 * NN * DD + bhn * DD + d);
  float inv = 1.0f / (LS[bhn] + LS[bhn + 64 * NN]);
  int bh = (int)(bhn >> 10), n = (int)(bhn & 1023);
  int bb = bh >> 3, head = bh & 7;
  su4v o;
#pragma unroll
  for (int r = 0; r < 4; ++r) o[r] = f2b((b2f(a[r]) + b2f(b[r])) * inv);
  *(su4v*)(AO + ((size_t)(bb * 1024 + n) * 1024) + head * 128 + d) = o;
}

// ---------------------------------------------------------------------------
// quaternion depthwise 3x3 conv (fp32) — writes PE term into workspace
// ---------------------------------------------------------------------------
__global__ __launch_bounds__(256) void qdwconv_kernel(
    const float* __restrict__ x, const float* __restrict__ wpe,
    const float* __restrict__ bpe, float* __restrict__ pe) {
  int blk = blockIdx.x;
  int co = blk & 255;
  int b = blk >> 8;
  __shared__ float pl[4][34 * 34];
  __shared__ float wsm[4][9];
  int tid = threadIdx.x;
  for (int i = tid; i < 4 * 34 * 34; i += 256) ((float*)pl)[i] = 0.f;
  if (tid < 36) wsm[tid / 9][tid % 9] = wpe[((tid / 9) * 256 + co) * 9 + tid % 9];
  __syncthreads();
  for (int i = tid; i < 4 * 1024; i += 256) {
    int p = i >> 10, n = i & 1023;
    int h = n >> 5, ww = n & 31;
    pl[p][(h + 1) * 34 + (ww + 1)] =
        x[(((size_t)b * 256 + co) * 4 + p) * 1024 + n];
  }
  __syncthreads();
  for (int n = tid; n < 1024; n += 256) {
    int h = n >> 5, ww = n & 31;
    float in[4][9];
#pragma unroll
    for (int p = 0; p < 4; ++p)
#pragma unroll
      for (int t = 0; t < 9; ++t)
        in[p][t] = pl[p][(h + t / 3) * 34 + (ww + t % 3)];
#pragma unroll
    for (int q = 0; q < 4; ++q) {
      float acc = bpe[q * 256 + co];
#pragma unroll
      for (int p = 0; p < 4; ++p) {
        int idx = d_IDX[q * 4 + p];
        float s = d_SGN[q * 4 + p];
        float sub = 0.f;
#pragma unroll
        for (int t = 0; t < 9; ++t) sub += in[p][t] * wsm[idx][t];
        acc += s * sub;
      }
      pe[(((size_t)b * 256 + co) * 4 + q) * 1024 + n] = acc;
    }
  }
}

// ---------------------------------------------------------------------------
// proj GEMM: tile = 256 (bn) x 128 (q,o). Grid 32x8 = 256 blocks.
// ---------------------------------------------------------------------------
__global__ __launch_bounds__(512, 2) void gemm_proj_mfma(
    const u16* __restrict__ AO, const u16* __restrict__ weffP,
    const float* __restrict__ bproj, const float* __restrict__ pe,
    float* __restrict__ out) {
  __shared__ u16 smem[3 * 384 * 64];  // 144 KB ring
  int n0 = blockIdx.x * 256;
  int m0 = blockIdx.y * 128;
  int tid = threadIdx.x;
  f32x4 acc[4][4];
#pragma unroll
  for (int i = 0; i < 4; ++i)
#pragma unroll
    for (int j = 0; j < 4; ++j) acc[i][j] = (f32x4){0.f, 0.f, 0.f, 0.f};
  gemm_core8<128, 256>(weffP + (size_t)m0 * 1024, AO + (size_t)n0 * 1024,
                       smem, smem + 3 * 128 * 64, tid, acc);

  int w = tid >> 6, lane = tid & 63, l16 = lane & 15, quad = lane >> 4;
  int wm = w >> 2, wn = w & 3;
#pragma unroll
  for (int i = 0; i < 4; ++i) {
#pragma unroll
    for (int r = 0; r < 4; ++r) {
      int mrow = m0 + wm * 64 + i * 16 + quad * 4 + r;
      int q = mrow >> 8, o = mrow & 255;
      float bias = bproj[mrow];
#pragma unroll
      for (int j = 0; j < 4; ++j) {
        int n = n0 + wn * 64 + j * 16 + l16;
        int b = n >> 10, npos = n & 1023;
        size_t oidx = (((size_t)b * 256 + o) * 4 + q) * 1024 + npos;
        out[oidx] = pe[oidx] + acc[i][j][r] + bias;
      }
    }
  }
}

// ---------------------------------------------------------------------------
extern "C" void kernel_launch(void* const* d_in, const int* in_sizes, int n_in,
                              void* d_out, int out_size, void* d_ws,
                              size_t ws_size, hipStream_t stream) {
  const float* x      = (const float*)d_in[0];
  const float* w_qkv  = (const float*)d_in[1];
  const float* b_qkv  = (const float*)d_in[2];
  const float* w_proj = (const float*)d_in[3];
  const float* b_proj = (const float*)d_in[4];
  const float* w_pe   = (const float*)d_in[5];
  const float* b_pe   = (const float*)d_in[6];
  float* out = (float*)d_out;

  u16* ws = (u16*)d_ws;
  u16* weffQ = ws;                                   // 3072*1024
  u16* weffP = weffQ + (size_t)H3 * DIM;             // 1024*1024
  u16* Ax    = weffP + (size_t)DIM * DIM;            // 8192*1024
  u16* Qb    = Ax + (size_t)MM * DIM;                // 64*1024*128
  u16* Kb    = Qb + (size_t)BB * NHD * NN * DD;      // 64*1024*128
  u16* VbT   = Kb + (size_t)BB * NHD * NN * DD;      // 64*128*1024
  u16* AO    = VbT + (size_t)BB * NHD * DD * NN;     // 8192*1024
  float* PE  = (float*)(AO + (size_t)MM * DIM);      // 8192*1024 fp32
  u16* OP    = (u16*)(PE + (size_t)MM * DIM);        // 2*64*1024*128 bf16
  float* LS  = (float*)(OP + (size_t)2 * 64 * NN * DD);  // 2*64*1024 fp32
  // total ~160 MB scratch

  hipLaunchKernelGGL(prep_weff, dim3(4096), dim3(256), 0, stream,
                     w_qkv, w_proj, weffQ, weffP);
  hipLaunchKernelGGL(prep_x, dim3(512), dim3(256), 0, stream, x, Ax);
  hipLaunchKernelGGL(gemm_qkv_mfma, dim3(MM / 256, H3 / 128), dim3(512), 0,
                     stream, Ax, weffQ, b_qkv, Qb, Kb, VbT);
  hipLaunchKernelGGL(attn_mfma, dim3(1024), dim3(256), 0, stream,
                     Qb, Kb, VbT, OP, LS);
  hipLaunchKernelGGL(attn_merge, dim3((64 * NN * DD) / (256 * 4)), dim3(256),
                     0, stream, OP, LS, AO);
  hipLaunchKernelGGL(qdwconv_kernel, dim3(BB * 256), dim3(256), 0, stream,
                     x, w_pe, b_pe, PE);
  hipLaunchKernelGGL(gemm_proj_mfma, dim3(MM / 256, DIM / 128), dim3(512), 0,
                     stream, AO, weffP, b_proj, PE, out);
}

// Round 10
// 283.621 us; speedup vs baseline: 1.0228x; 1.0228x over previous
//
#include <hip/hip_runtime.h>
#include <hip/hip_bf16.h>

typedef unsigned short u16;
typedef float f32x4 __attribute__((ext_vector_type(4)));
typedef __bf16 bf16x8 __attribute__((ext_vector_type(8)));
typedef __bf16 bf16x4 __attribute__((ext_vector_type(4)));
typedef unsigned short su8v __attribute__((ext_vector_type(8)));
typedef unsigned short su4v __attribute__((ext_vector_type(4)));
typedef short s16x4 __attribute__((ext_vector_type(4)));

#define BB 8
#define NHD 8
#define DD 128
#define NN 1024
#define DIM 1024
#define H3 3072
#define MM 8192
// scale * log2(e), folded into Q weights so softmax is exp2(raw dot)
#define QSC (0.08838834764831845f * 1.4426950408889634f)

__constant__ int   d_IDX[16] = {0,1,2,3, 1,0,3,2, 2,3,0,1, 3,2,1,0};
__constant__ float d_SGN[16] = {1.f,-1.f,-1.f,-1.f, 1.f,1.f,1.f,-1.f,
                                1.f,-1.f,1.f,1.f,  1.f,1.f,-1.f,1.f};

__device__ __forceinline__ f32x4 mfma16(su8v a, su8v b, f32x4 c) {
  return __builtin_amdgcn_mfma_f32_16x16x32_bf16(
      __builtin_bit_cast(bf16x8, a), __builtin_bit_cast(bf16x8, b), c, 0, 0, 0);
}
// 16x16x16 bf16 MFMA (K=16): A/B are 4 bf16 (2 VGPRs). Used for PV so the
// QK^T output registers feed PV directly (lane: m=l16, k=quad*4+e).
__device__ __forceinline__ f32x4 mfma16h(su4v a, su4v b, f32x4 c) {
#if __has_builtin(__builtin_amdgcn_mfma_f32_16x16x16_bf16)
  return __builtin_amdgcn_mfma_f32_16x16x16_bf16(
      __builtin_bit_cast(bf16x4, a), __builtin_bit_cast(bf16x4, b), c, 0, 0, 0);
#elif __has_builtin(__builtin_amdgcn_mfma_f32_16x16x16bf16_1k)
  return __builtin_amdgcn_mfma_f32_16x16x16bf16_1k(
      __builtin_bit_cast(s16x4, a), __builtin_bit_cast(s16x4, b), c, 0, 0, 0);
#else
  f32x4 d = c;
  asm("v_mfma_f32_16x16x16_bf16 %0, %1, %2, %0" : "+v"(d) : "v"(a), "v"(b));
  return d;
#endif
}
__device__ __forceinline__ u16 f2b(float f) {  // RNE
  unsigned int u = __builtin_bit_cast(unsigned int, f);
  u += 0x7fffu + ((u >> 16) & 1u);
  return (u16)(u >> 16);
}
__device__ __forceinline__ float b2f(u16 v) {
  unsigned int u = ((unsigned int)v) << 16;
  return __builtin_bit_cast(float, u);
}
typedef const __attribute__((address_space(1))) unsigned int* gas_t;
typedef __attribute__((address_space(3))) unsigned int* las_t;
__device__ __forceinline__ void gll16(const u16* g, u16* l) {
  __builtin_amdgcn_global_load_lds((gas_t)g, (las_t)l, 16, 0, 0);
}

// ---------------------------------------------------------------------------
// prep_weff: effective weights [out_row][in_col] bf16; Q-rows pre-scaled by QSC
// ---------------------------------------------------------------------------
__global__ __launch_bounds__(256) void prep_weff(
    const float* __restrict__ wqkv, const float* __restrict__ wproj,
    u16* __restrict__ weffQ, u16* __restrict__ weffP) {
  int tid = blockIdx.x * 256 + threadIdx.x;
  int stride = gridDim.x * 256;
  for (int i = tid; i < H3 * DIM; i += stride) {
    int row = i >> 10, col = i & 1023;
    int q = row / 768, o = row - q * 768;
    int p = col >> 8, c = col & 255;
    float v = d_SGN[q * 4 + p] * wqkv[(d_IDX[q * 4 + p] * 768 + o) * 256 + c];
    if (o < 256) v *= QSC;  // Q rows
    weffQ[i] = f2b(v);
  }
  for (int i = tid; i < DIM * DIM; i += stride) {
    int row = i >> 10, col = i & 1023;
    int q = row >> 8, o = row & 255;
    int p = col >> 8, c = col & 255;
    weffP[i] = f2b(d_SGN[q * 4 + p] * wproj[(d_IDX[q * 4 + p] * 256 + o) * 256 + c]);
  }
}

// ---------------------------------------------------------------------------
// prep_x: x (B,Cc,4,N) fp32 -> Ax bf16 [8192 (b,n)][1024 (p,c)].
// LDS transpose, layout T[n][pc] stride 264 u16 (16B-aligned su8v reads).
// ---------------------------------------------------------------------------
__global__ __launch_bounds__(256) void prep_x(
    const float* __restrict__ x, u16* __restrict__ Ax) {
  __shared__ u16 T[64 * 264];  // [n][pc], stride 264
  int blk = blockIdx.x;
  int nc = blk & 15;
  int cc = (blk >> 4) & 3;
  int b = blk >> 6;
  int n0 = nc * 64, c0 = cc * 64;
  int tid = threadIdx.x;
  int nseg = tid & 15, rq = tid >> 4;  // rq 0..15
#pragma unroll
  for (int pass = 0; pass < 16; ++pass) {
    int rr = pass * 16 + rq;  // pc local 0..255: p = rr>>6, c = rr&63
    int p = rr >> 6, c = rr & 63;
    float4 f = *(const float4*)(x + (((size_t)(b * 256 + c0 + c)) * 4 + p) * 1024 +
                                n0 + nseg * 4);
    T[(nseg * 4 + 0) * 264 + rr] = f2b(f.x);
    T[(nseg * 4 + 1) * 264 + rr] = f2b(f.y);
    T[(nseg * 4 + 2) * 264 + rr] = f2b(f.z);
    T[(nseg * 4 + 3) * 264 + rr] = f2b(f.w);
  }
  __syncthreads();
  int nl = tid >> 5, lc = tid & 31;
#pragma unroll
  for (int pass = 0; pass < 8; ++pass) {
    int n = pass * 8 + nl;
    su8v v = *(const su8v*)(&T[n * 264 + lc * 8]);
    int pcl = lc * 8;
    *(su8v*)(Ax + (size_t)(b * 1024 + n0 + n) * 1024 + (pcl >> 6) * 256 + c0 +
             (pcl & 63)) = v;
  }
}

// ---------------------------------------------------------------------------
// 8-wave GEMM core, ONE barrier per K-tile + counted vmcnt, free-running
// waves. Tile BM x BN (BM+BN == 384), BK=64, 512 threads = 8 waves of 64x64.
// 3-slot LDS ring; loads for 2 future tiles stay in flight across barriers.
// LDS rows 64 u16 = 8 x 16B blocks, XOR-swizzled (blk ^= row&7); global
// source pre-swizzled identically so gll's linear LDS write lands right.
// ---------------------------------------------------------------------------
template <int BM, int BN>
__device__ __forceinline__ void gemm_core8(
    const u16* __restrict__ Ag, const u16* __restrict__ Bg,
    u16* As, u16* Bs, int tid, f32x4 (&acc)[4][4]) {
  constexpr int WN = BN / 64;
  constexpr int AC = BM / 64;
  constexpr int BC = BN / 64;
  constexpr int NT = 16;  // K = 1024 / BK(64)
  int w = tid >> 6, lane = tid & 63, l16 = lane & 15, quad = lane >> 4;
  int wm = w / WN, wn = w % WN;
  int x7 = l16 & 7;
  int srow = lane >> 3;
  int sblk = (lane & 7) ^ srow;

  auto STAGE_A = [&](int tt, int bs) {
#pragma unroll
    for (int c = 0; c < AC; ++c) {
      int r0 = c * 64 + w * 8;
      gll16(Ag + (size_t)(r0 + srow) * 1024 + tt * 64 + sblk * 8,
            As + (size_t)bs * (BM * 64) + r0 * 64);
    }
  };
  auto STAGE_B = [&](int tt, int bs) {
#pragma unroll
    for (int c = 0; c < BC; ++c) {
      int r0 = c * 64 + w * 8;
      gll16(Bg + (size_t)(r0 + srow) * 1024 + tt * 64 + sblk * 8,
            Bs + (size_t)bs * (BN * 64) + r0 * 64);
    }
  };

  STAGE_A(0, 0); STAGE_B(0, 0);
  STAGE_A(1, 1); STAGE_B(1, 1);
  asm volatile("s_waitcnt vmcnt(6)" ::: "memory");
  __builtin_amdgcn_s_barrier();

  int cur = 0, nxt = 1, stg = 2;
  for (int t = 0; t < NT; ++t) {
    const u16* At = As + (size_t)cur * (BM * 64);
    const u16* Bt = Bs + (size_t)cur * (BN * 64);
#pragma unroll
    for (int kk = 0; kk < 2; ++kk) {
      su8v af[4], bf[4];
#pragma unroll
      for (int i = 0; i < 4; ++i)
        af[i] = *(const su8v*)(At + (wm * 64 + i * 16 + l16) * 64 +
                               ((kk * 4 + quad) ^ x7) * 8);
#pragma unroll
      for (int j = 0; j < 4; ++j)
        bf[j] = *(const su8v*)(Bt + (wn * 64 + j * 16 + l16) * 64 +
                               ((kk * 4 + quad) ^ x7) * 8);
      if (t + 2 < NT) {
        if (kk == 0) STAGE_A(t + 2, stg);
        else         STAGE_B(t + 2, stg);
      }
      __builtin_amdgcn_s_setprio(1);
#pragma unroll
      for (int i = 0; i < 4; ++i)
#pragma unroll
        for (int j = 0; j < 4; ++j)
          acc[i][j] = mfma16(af[i], bf[j], acc[i][j]);
      __builtin_amdgcn_s_setprio(0);
    }
    if (t < NT - 2)       asm volatile("s_waitcnt vmcnt(6)" ::: "memory");
    else if (t == NT - 2) asm volatile("s_waitcnt vmcnt(0)" ::: "memory");
    asm volatile("" ::: "memory");
    __builtin_amdgcn_s_barrier();
    asm volatile("" ::: "memory");
    int tmp = cur; cur = nxt; nxt = stg; stg = tmp;
  }
}

// ---------------------------------------------------------------------------
// QKV GEMM: tile = 256 (bn) x 128 (chan). Grid 32x24 = 768 blocks.
// V stored plain [bh][d][npos] (round-8 half-swap removed; attn's new Vt
// layout uses an even XOR key so staged blocks stay key-linear).
// ---------------------------------------------------------------------------
__global__ __launch_bounds__(512, 2) void gemm_qkv_mfma(
    const u16* __restrict__ Ax, const u16* __restrict__ weffQ,
    const float* __restrict__ bqkv,
    u16* __restrict__ Qb, u16* __restrict__ Kb, u16* __restrict__ VbT) {
  __shared__ u16 smem[3 * 384 * 64];  // 144 KB: 3-slot ring, A tile + B tile
  int bn0 = blockIdx.x * 256;
  int col0 = blockIdx.y * 128;
  int q = col0 / 768;
  int off = col0 - q * 768;
  int sel = off >> 8;  // 0=Q 1=K 2=V (uniform)
  int head = (q * 256 + (off & 255)) >> 7;
  int tid = threadIdx.x;
  int w = tid >> 6, lane = tid & 63, l16 = lane & 15, quad = lane >> 4;
  f32x4 acc[4][4];
#pragma unroll
  for (int i = 0; i < 4; ++i)
#pragma unroll
    for (int j = 0; j < 4; ++j) acc[i][j] = (f32x4){0.f, 0.f, 0.f, 0.f};

  if (sel == 2) {
    // ---- V: m=bn (256), n=chan (128) ----
    gemm_core8<256, 128>(Ax + (size_t)bn0 * 1024, weffQ + (size_t)col0 * 1024,
                         smem, smem + 3 * 256 * 64, tid, acc);
    int wm = w >> 1, wn = w & 1;
#pragma unroll
    for (int j = 0; j < 4; ++j) {
      int dl = wn * 64 + j * 16 + l16;
      float bias = bqkv[col0 + dl];
#pragma unroll
      for (int i = 0; i < 4; ++i) {
        int m = bn0 + wm * 64 + i * 16 + quad * 4;
        int b = m >> 10, npos = m & 1023;
        int bh = b * NHD + head;
        su4v pk;
#pragma unroll
        for (int r = 0; r < 4; ++r) pk[r] = f2b(acc[i][j][r] + bias);
        *(su4v*)(VbT + ((size_t)bh * DD + dl) * NN + npos) = pk;
      }
    }
  } else {
    // ---- Q/K: m=chan (128), n=bn (256) ----
    gemm_core8<128, 256>(weffQ + (size_t)col0 * 1024, Ax + (size_t)bn0 * 1024,
                         smem, smem + 3 * 128 * 64, tid, acc);
    int wm = w >> 2, wn = w & 3;
    u16* dst = (sel == 0) ? Qb : Kb;
    float sc = (sel == 0) ? (float)QSC : 1.0f;
#pragma unroll
    for (int i = 0; i < 4; ++i) {
      int dbase = wm * 64 + i * 16 + quad * 4;
      float4 b4 = *(const float4*)(bqkv + col0 + dbase);
#pragma unroll
      for (int j = 0; j < 4; ++j) {
        int n = bn0 + wn * 64 + j * 16 + l16;
        int b = n >> 10, npos = n & 1023;
        int bh = b * NHD + head;
        su4v pk;
        pk[0] = f2b(acc[i][j][0] + b4.x * sc);
        pk[1] = f2b(acc[i][j][1] + b4.y * sc);
        pk[2] = f2b(acc[i][j][2] + b4.z * sc);
        pk[3] = f2b(acc[i][j][3] + b4.w * sc);
        *(su4v*)(dst + ((size_t)bh * NN + npos) * DD + dbase) = pk;
      }
    }
  }
}

// ---------------------------------------------------------------------------
// Flash attention, split-K x2: 1024 blocks = half(2) x qt(8) x bh(64).
// 128 q x 512 keys per block, KVBLK=32 -> 16 K-tiles. PIPELINED like the
// GEMM core: 3-slot LDS ring (48 KB; registers, not LDS, bind occupancy),
// STAGE(kt+2) issued at top of kt, counted vmcnt(4) + ONE barrier per tile
// (round-9: per-kt stage-then-drain was the ~37us stall; MfmaUtil 32%).
// In-register P (QK^T S^T lane layout == K=16 A-fragment), ones-MFMA rowsum.
// Bank layout (all <=2-way == free):
//  - Ks rows 256B = 16 blocks, slot = blk ^ (key&15) (round-9, measured 0).
//  - Vt rows 64B = 8 granules of 8B; granule slot = nat ^ (d&6): 8 distinct
//    even bank-starts per 16-lane phase, l16/l16+8 pair = free 2-way. XOR
//    key is EVEN -> staged 16B blocks stay key-linear -> plain global V.
// No launch_bounds min-waves (rounds 6/7: caps below natural regs => spill).
// ---------------------------------------------------------------------------
__global__ __launch_bounds__(256) void attn_mfma(
    const u16* __restrict__ Qb, const u16* __restrict__ Kb,
    const u16* __restrict__ VbT, u16* __restrict__ OP,
    float* __restrict__ LS) {
  __shared__ u16 Ks[3 * 32 * 128];  // 24 KB ring, 4-bit xor-swizzled blocks
  __shared__ u16 Vt[3 * 128 * 32];  // 24 KB ring, even-xor granule swizzle
  int blk = blockIdx.x;
  int bh = blk & 63;  // low bits -> blk%8 == bh%8 (same XCD for K/V L2 reuse)
  int rest = blk >> 6;
  int qt = rest & 7;
  int half = rest >> 3;
  int n0 = qt * 128;
  int tid = threadIdx.x;
  int w = tid >> 6, lane = tid & 63, l16 = lane & 15, quad = lane >> 4;
  const u16* Qg = Qb + ((size_t)bh * NN + n0) * DD;
  const u16* Kg = Kb + (size_t)bh * NN * DD;
  const u16* Vg = VbT + (size_t)bh * DD * NN;

  auto STAGE = [&](int kt, int s) {
    int c0 = half * 512 + kt * 32;
#pragma unroll
    for (int t = 0; t < 2; ++t) {
      int ci = w * 2 + t;  // 0..7
      // K: 1KB = 4 rows x 256B; block slot holds global blk^(key&15)
      int krow = ci * 4 + (lane >> 4);
      int kblk = (lane & 15) ^ (krow & 15);
      gll16(Kg + (size_t)(c0 + krow) * DD + kblk * 8, Ks + s * 4096 + ci * 512);
      // V: 1KB = 16 rows x 64B; 16B block slot holds keys 8*(b^((d>>1)&3))
      int dv = ci * 16 + (lane >> 2);
      int vblk = (lane & 3) ^ ((dv >> 1) & 3);
      gll16(Vg + (size_t)dv * NN + c0 + vblk * 8, Vt + s * 4096 + ci * 512);
    }
  };

  su8v qreg[2][4];  // B-fragment: n=q (l16), k=d
#pragma unroll
  for (int mi = 0; mi < 2; ++mi)
#pragma unroll
    for (int ch = 0; ch < 4; ++ch)
      qreg[mi][ch] = *(const su8v*)(Qg + (size_t)(w * 32 + mi * 16 + l16) * DD +
                                    ch * 32 + quad * 8);

  su4v ones;
  ones[0] = 0x3F80; ones[1] = 0x3F80; ones[2] = 0x3F80; ones[3] = 0x3F80;
  f32x4 accL[2];
  accL[0] = (f32x4){0.f, 0.f, 0.f, 0.f};
  accL[1] = (f32x4){0.f, 0.f, 0.f, 0.f};
  f32x4 accO[2][8];
#pragma unroll
  for (int mi = 0; mi < 2; ++mi)
#pragma unroll
    for (int dt = 0; dt < 8; ++dt) accO[mi][dt] = (f32x4){0.f, 0.f, 0.f, 0.f};

  STAGE(0, 0); STAGE(1, 1);
  asm volatile("s_waitcnt vmcnt(4)" ::: "memory");
  __builtin_amdgcn_s_barrier();

  int cur = 0, nxt = 1, stg = 2;
  for (int kt = 0; kt < 16; ++kt) {
    const u16* Kc = Ks + cur * 4096;
    const u16* Vc = Vt + cur * 4096;
    if (kt + 2 < 16) STAGE(kt + 2, stg);

    // fused per-16-key-slice: QK^T -> exp2/pack -> PV + ones-MFMA row-sum
#pragma unroll
    for (int j = 0; j < 2; ++j) {
      f32x4 s0 = (f32x4){0.f, 0.f, 0.f, 0.f};
      f32x4 s1 = (f32x4){0.f, 0.f, 0.f, 0.f};
#pragma unroll
      for (int ch = 0; ch < 4; ++ch) {
        su8v kf = *(const su8v*)(Kc + (j * 16 + l16) * 128 +
                                 (((ch * 4 + quad) ^ l16) * 8));
        s0 = mfma16(kf, qreg[0][ch], s0);
        s1 = mfma16(kf, qreg[1][ch], s1);
      }
      su4v p0, p1;
#pragma unroll
      for (int r = 0; r < 4; ++r) {
        float pa = __builtin_exp2f(s0[r]);
        p0[r] = (u16)(__builtin_bit_cast(unsigned int, pa) >> 16);
        float pb = __builtin_exp2f(s1[r]);
        p1[r] = (u16)(__builtin_bit_cast(unsigned int, pb) >> 16);
      }
      accL[0] = mfma16h(p0, ones, accL[0]);
      accL[1] = mfma16h(p1, ones, accL[1]);
#pragma unroll
      for (int dt = 0; dt < 8; ++dt) {
        su4v vf = *(const su4v*)(Vc + (dt * 16 + l16) * 32 +
                                 (((j * 4 + quad) ^ (l16 & 6)) * 4));
        accO[0][dt] = mfma16h(p0, vf, accO[0][dt]);
        accO[1][dt] = mfma16h(p1, vf, accO[1][dt]);
      }
    }

    if (kt < 14)       asm volatile("s_waitcnt vmcnt(4)" ::: "memory");
    else if (kt == 14) asm volatile("s_waitcnt vmcnt(0)" ::: "memory");
    if (kt < 15) {
      asm volatile("" ::: "memory");
      __builtin_amdgcn_s_barrier();
      asm volatile("" ::: "memory");
    }
    int tmp = cur; cur = nxt; nxt = stg; stg = tmp;
  }

  size_t hb = (size_t)(half * 64 + bh);
  // accL: lane (l16,quad) holds row-sums for q rows quad*4+r (all l16 equal)
  if (l16 == 0) {
#pragma unroll
    for (int mi = 0; mi < 2; ++mi)
      *(float4*)(&LS[hb * NN + n0 + w * 32 + mi * 16 + quad * 4]) =
          *(float4*)(&accL[mi]);
  }
  // store unnormalized O partial (bf16)
#pragma unroll
  for (int mi = 0; mi < 2; ++mi)
#pragma unroll
    for (int r = 0; r < 4; ++r) {
      int row = w * 32 + mi * 16 + quad * 4 + r;
      size_t base = (hb * NN + n0 + row) * DD;
#pragma unroll
      for (int dt = 0; dt < 8; ++dt)
        OP[base + dt * 16 + l16] = f2b(accO[mi][dt][r]);
    }
}

// ---------------------------------------------------------------------------
// merge: AO[b,n][head*128+d] = (O0 + O1) / (l0 + l1)
// ---------------------------------------------------------------------------
__global__ __launch_bounds__(256) void attn_merge(
    const u16* __restrict__ OP, const float* __restrict__ LS,
    u16* __restrict__ AO) {
  size_t idx = (size_t)blockIdx.x * 256 + threadIdx.x;  // 4-elem chunk id
  size_t e = idx * 4;
  int d = (int)(e & 127);
  size_t bhn = e >> 7;  // bh*1024 + n
  su4v a = *(const su4v*)(OP + bhn * DD + d);
  su4v b = *(const su4v*)(OP + (size_t)64 * NN * DD + bhn * DD + d);
  float inv = 1.0f / (LS[bhn] + LS[bhn + 64 * NN]);
  int bh = (int)(bhn >> 10), n = (int)(bhn & 1023);
  int bb = bh >> 3, head = bh & 7;
  su4v o;
#pragma unroll
  for (int r = 0; r < 4; ++r) o[r] = f2b((b2f(a[r]) + b2f(b[r])) * inv);
  *(su4v*)(AO + ((size_t)(bb * 1024 + n) * 1024) + head * 128 + d) = o;
}

// ---------------------------------------------------------------------------
// quaternion depthwise 3x3 conv (fp32) — writes PE term into workspace
// ---------------------------------------------------------------------------
__global__ __launch_bounds__(256) void qdwconv_kernel(
    const float* __restrict__ x, const float* __restrict__ wpe,
    const float* __restrict__ bpe, float* __restrict__ pe) {
  int blk = blockIdx.x;
  int co = blk & 255;
  int b = blk >> 8;
  __shared__ float pl[4][34 * 34];
  __shared__ float wsm[4][9];
  int tid = threadIdx.x;
  for (int i = tid; i < 4 * 34 * 34; i += 256) ((float*)pl)[i] = 0.f;
  if (tid < 36) wsm[tid / 9][tid % 9] = wpe[((tid / 9) * 256 + co) * 9 + tid % 9];
  __syncthreads();
  for (int i = tid; i < 4 * 1024; i += 256) {
    int p = i >> 10, n = i & 1023;
    int h = n >> 5, ww = n & 31;
    pl[p][(h + 1) * 34 + (ww + 1)] =
        x[(((size_t)b * 256 + co) * 4 + p) * 1024 + n];
  }
  __syncthreads();
  for (int n = tid; n < 1024; n += 256) {
    int h = n >> 5, ww = n & 31;
    float in[4][9];
#pragma unroll
    for (int p = 0; p < 4; ++p)
#pragma unroll
      for (int t = 0; t < 9; ++t)
        in[p][t] = pl[p][(h + t / 3) * 34 + (ww + t % 3)];
#pragma unroll
    for (int q = 0; q < 4; ++q) {
      float acc = bpe[q * 256 + co];
#pragma unroll
      for (int p = 0; p < 4; ++p) {
        int idx = d_IDX[q * 4 + p];
        float s = d_SGN[q * 4 + p];
        float sub = 0.f;
#pragma unroll
        for (int t = 0; t < 9; ++t) sub += in[p][t] * wsm[idx][t];
        acc += s * sub;
      }
      pe[(((size_t)b * 256 + co) * 4 + q) * 1024 + n] = acc;
    }
  }
}

// ---------------------------------------------------------------------------
// proj GEMM: tile = 256 (bn) x 128 (q,o). Grid 32x8 = 256 blocks.
// ---------------------------------------------------------------------------
__global__ __launch_bounds__(512, 2) void gemm_proj_mfma(
    const u16* __restrict__ AO, const u16* __restrict__ weffP,
    const float* __restrict__ bproj, const float* __restrict__ pe,
    float* __restrict__ out) {
  __shared__ u16 smem[3 * 384 * 64];  // 144 KB ring
  int n0 = blockIdx.x * 256;
  int m0 = blockIdx.y * 128;
  int tid = threadIdx.x;
  f32x4 acc[4][4];
#pragma unroll
  for (int i = 0; i < 4; ++i)
#pragma unroll
    for (int j = 0; j < 4; ++j) acc[i][j] = (f32x4){0.f, 0.f, 0.f, 0.f};
  gemm_core8<128, 256>(weffP + (size_t)m0 * 1024, AO + (size_t)n0 * 1024,
                       smem, smem + 3 * 128 * 64, tid, acc);

  int w = tid >> 6, lane = tid & 63, l16 = lane & 15, quad = lane >> 4;
  int wm = w >> 2, wn = w & 3;
#pragma unroll
  for (int i = 0; i < 4; ++i) {
#pragma unroll
    for (int r = 0; r < 4; ++r) {
      int mrow = m0 + wm * 64 + i * 16 + quad * 4 + r;
      int q = mrow >> 8, o = mrow & 255;
      float bias = bproj[mrow];
#pragma unroll
      for (int j = 0; j < 4; ++j) {
        int n = n0 + wn * 64 + j * 16 + l16;
        int b = n >> 10, npos = n & 1023;
        size_t oidx = (((size_t)b * 256 + o) * 4 + q) * 1024 + npos;
        out[oidx] = pe[oidx] + acc[i][j][r] + bias;
      }
    }
  }
}

// ---------------------------------------------------------------------------
extern "C" void kernel_launch(void* const* d_in, const int* in_sizes, int n_in,
                              void* d_out, int out_size, void* d_ws,
                              size_t ws_size, hipStream_t stream) {
  const float* x      = (const float*)d_in[0];
  const float* w_qkv  = (const float*)d_in[1];
  const float* b_qkv  = (const float*)d_in[2];
  const float* w_proj = (const float*)d_in[3];
  const float* b_proj = (const float*)d_in[4];
  const float* w_pe   = (const float*)d_in[5];
  const float* b_pe   = (const float*)d_in[6];
  float* out = (float*)d_out;

  u16* ws = (u16*)d_ws;
  u16* weffQ = ws;                                   // 3072*1024
  u16* weffP = weffQ + (size_t)H3 * DIM;             // 1024*1024
  u16* Ax    = weffP + (size_t)DIM * DIM;            // 8192*1024
  u16* Qb    = Ax + (size_t)MM * DIM;                // 64*1024*128
  u16* Kb    = Qb + (size_t)BB * NHD * NN * DD;      // 64*1024*128
  u16* VbT   = Kb + (size_t)BB * NHD * NN * DD;      // 64*128*1024
  u16* AO    = VbT + (size_t)BB * NHD * DD * NN;     // 8192*1024
  float* PE  = (float*)(AO + (size_t)MM * DIM);      // 8192*1024 fp32
  u16* OP    = (u16*)(PE + (size_t)MM * DIM);        // 2*64*1024*128 bf16
  float* LS  = (float*)(OP + (size_t)2 * 64 * NN * DD);  // 2*64*1024 fp32
  // total ~160 MB scratch

  hipLaunchKernelGGL(prep_weff, dim3(4096), dim3(256), 0, stream,
                     w_qkv, w_proj, weffQ, weffP);
  hipLaunchKernelGGL(prep_x, dim3(512), dim3(256), 0, stream, x, Ax);
  hipLaunchKernelGGL(gemm_qkv_mfma, dim3(MM / 256, H3 / 128), dim3(512), 0,
                     stream, Ax, weffQ, b_qkv, Qb, Kb, VbT);
  hipLaunchKernelGGL(attn_mfma, dim3(1024), dim3(256), 0, stream,
                     Qb, Kb, VbT, OP, LS);
  hipLaunchKernelGGL(attn_merge, dim3((64 * NN * DD) / (256 * 4)), dim3(256),
                     0, stream, OP, LS, AO);
  hipLaunchKernelGGL(qdwconv_kernel, dim3(BB * 256), dim3(256), 0, stream,
                     x, w_pe, b_pe, PE);
  hipLaunchKernelGGL(gemm_proj_mfma, dim3(MM / 256, DIM / 128), dim3(512), 0,
                     stream, AO, weffP, b_proj, PE, out);
}

// Round 11
// 272.800 us; speedup vs baseline: 1.0634x; 1.0397x over previous
//
#include <hip/hip_runtime.h>
#include <hip/hip_bf16.h>

typedef unsigned short u16;
typedef float f32x4 __attribute__((ext_vector_type(4)));
typedef __bf16 bf16x8 __attribute__((ext_vector_type(8)));
typedef __bf16 bf16x4 __attribute__((ext_vector_type(4)));
typedef unsigned short su8v __attribute__((ext_vector_type(8)));
typedef unsigned short su4v __attribute__((ext_vector_type(4)));
typedef short s16x4 __attribute__((ext_vector_type(4)));

#define BB 8
#define NHD 8
#define DD 128
#define NN 1024
#define DIM 1024
#define H3 3072
#define MM 8192
// scale * log2(e), folded into Q weights so softmax is exp2(raw dot)
#define QSC (0.08838834764831845f * 1.4426950408889634f)

__constant__ int   d_IDX[16] = {0,1,2,3, 1,0,3,2, 2,3,0,1, 3,2,1,0};
__constant__ float d_SGN[16] = {1.f,-1.f,-1.f,-1.f, 1.f,1.f,1.f,-1.f,
                                1.f,-1.f,1.f,1.f,  1.f,1.f,-1.f,1.f};

__device__ __forceinline__ f32x4 mfma16(su8v a, su8v b, f32x4 c) {
  return __builtin_amdgcn_mfma_f32_16x16x32_bf16(
      __builtin_bit_cast(bf16x8, a), __builtin_bit_cast(bf16x8, b), c, 0, 0, 0);
}
// 16x16x16 bf16 MFMA (K=16): A/B are 4 bf16 (2 VGPRs). Used for PV so the
// QK^T output registers feed PV directly (lane: m=l16, k=quad*4+e).
__device__ __forceinline__ f32x4 mfma16h(su4v a, su4v b, f32x4 c) {
#if __has_builtin(__builtin_amdgcn_mfma_f32_16x16x16_bf16)
  return __builtin_amdgcn_mfma_f32_16x16x16_bf16(
      __builtin_bit_cast(bf16x4, a), __builtin_bit_cast(bf16x4, b), c, 0, 0, 0);
#elif __has_builtin(__builtin_amdgcn_mfma_f32_16x16x16bf16_1k)
  return __builtin_amdgcn_mfma_f32_16x16x16bf16_1k(
      __builtin_bit_cast(s16x4, a), __builtin_bit_cast(s16x4, b), c, 0, 0, 0);
#else
  f32x4 d = c;
  asm("v_mfma_f32_16x16x16_bf16 %0, %1, %2, %0" : "+v"(d) : "v"(a), "v"(b));
  return d;
#endif
}
__device__ __forceinline__ u16 f2b(float f) {  // RNE
  unsigned int u = __builtin_bit_cast(unsigned int, f);
  u += 0x7fffu + ((u >> 16) & 1u);
  return (u16)(u >> 16);
}
__device__ __forceinline__ float b2f(u16 v) {
  unsigned int u = ((unsigned int)v) << 16;
  return __builtin_bit_cast(float, u);
}
typedef const __attribute__((address_space(1))) unsigned int* gas_t;
typedef __attribute__((address_space(3))) unsigned int* las_t;
__device__ __forceinline__ void gll16(const u16* g, u16* l) {
  __builtin_amdgcn_global_load_lds((gas_t)g, (las_t)l, 16, 0, 0);
}

// ---------------------------------------------------------------------------
// prep_weff: effective weights [out_row][in_col] bf16; Q-rows pre-scaled by QSC
// ---------------------------------------------------------------------------
__global__ __launch_bounds__(256) void prep_weff(
    const float* __restrict__ wqkv, const float* __restrict__ wproj,
    u16* __restrict__ weffQ, u16* __restrict__ weffP) {
  int tid = blockIdx.x * 256 + threadIdx.x;
  int stride = gridDim.x * 256;
  for (int i = tid; i < H3 * DIM; i += stride) {
    int row = i >> 10, col = i & 1023;
    int q = row / 768, o = row - q * 768;
    int p = col >> 8, c = col & 255;
    float v = d_SGN[q * 4 + p] * wqkv[(d_IDX[q * 4 + p] * 768 + o) * 256 + c];
    if (o < 256) v *= QSC;  // Q rows
    weffQ[i] = f2b(v);
  }
  for (int i = tid; i < DIM * DIM; i += stride) {
    int row = i >> 10, col = i & 1023;
    int q = row >> 8, o = row & 255;
    int p = col >> 8, c = col & 255;
    weffP[i] = f2b(d_SGN[q * 4 + p] * wproj[(d_IDX[q * 4 + p] * 256 + o) * 256 + c]);
  }
}

// ---------------------------------------------------------------------------
// prep_x: x (B,Cc,4,N) fp32 -> Ax bf16 [8192 (b,n)][1024 (p,c)].
// LDS transpose, layout T[n][pc] stride 264 u16 (16B-aligned su8v reads).
// ---------------------------------------------------------------------------
__global__ __launch_bounds__(256) void prep_x(
    const float* __restrict__ x, u16* __restrict__ Ax) {
  __shared__ u16 T[64 * 264];  // [n][pc], stride 264
  int blk = blockIdx.x;
  int nc = blk & 15;
  int cc = (blk >> 4) & 3;
  int b = blk >> 6;
  int n0 = nc * 64, c0 = cc * 64;
  int tid = threadIdx.x;
  int nseg = tid & 15, rq = tid >> 4;  // rq 0..15
#pragma unroll
  for (int pass = 0; pass < 16; ++pass) {
    int rr = pass * 16 + rq;  // pc local 0..255: p = rr>>6, c = rr&63
    int p = rr >> 6, c = rr & 63;
    float4 f = *(const float4*)(x + (((size_t)(b * 256 + c0 + c)) * 4 + p) * 1024 +
                                n0 + nseg * 4);
    T[(nseg * 4 + 0) * 264 + rr] = f2b(f.x);
    T[(nseg * 4 + 1) * 264 + rr] = f2b(f.y);
    T[(nseg * 4 + 2) * 264 + rr] = f2b(f.z);
    T[(nseg * 4 + 3) * 264 + rr] = f2b(f.w);
  }
  __syncthreads();
  int nl = tid >> 5, lc = tid & 31;
#pragma unroll
  for (int pass = 0; pass < 8; ++pass) {
    int n = pass * 8 + nl;
    su8v v = *(const su8v*)(&T[n * 264 + lc * 8]);
    int pcl = lc * 8;
    *(su8v*)(Ax + (size_t)(b * 1024 + n0 + n) * 1024 + (pcl >> 6) * 256 + c0 +
             (pcl & 63)) = v;
  }
}

// ---------------------------------------------------------------------------
// 8-wave GEMM core, ONE barrier per K-tile + counted vmcnt, free-running
// waves. Tile BM x BN (BM+BN == 384), BK=64, 512 threads = 8 waves of 64x64.
// 3-slot LDS ring; loads for 2 future tiles stay in flight across barriers.
// LDS rows 64 u16 = 8 x 16B blocks, XOR-swizzled (blk ^= row&7); global
// source pre-swizzled identically so gll's linear LDS write lands right.
// ---------------------------------------------------------------------------
template <int BM, int BN>
__device__ __forceinline__ void gemm_core8(
    const u16* __restrict__ Ag, const u16* __restrict__ Bg,
    u16* As, u16* Bs, int tid, f32x4 (&acc)[4][4]) {
  constexpr int WN = BN / 64;
  constexpr int AC = BM / 64;
  constexpr int BC = BN / 64;
  constexpr int NT = 16;  // K = 1024 / BK(64)
  int w = tid >> 6, lane = tid & 63, l16 = lane & 15, quad = lane >> 4;
  int wm = w / WN, wn = w % WN;
  int x7 = l16 & 7;
  int srow = lane >> 3;
  int sblk = (lane & 7) ^ srow;

  auto STAGE_A = [&](int tt, int bs) {
#pragma unroll
    for (int c = 0; c < AC; ++c) {
      int r0 = c * 64 + w * 8;
      gll16(Ag + (size_t)(r0 + srow) * 1024 + tt * 64 + sblk * 8,
            As + (size_t)bs * (BM * 64) + r0 * 64);
    }
  };
  auto STAGE_B = [&](int tt, int bs) {
#pragma unroll
    for (int c = 0; c < BC; ++c) {
      int r0 = c * 64 + w * 8;
      gll16(Bg + (size_t)(r0 + srow) * 1024 + tt * 64 + sblk * 8,
            Bs + (size_t)bs * (BN * 64) + r0 * 64);
    }
  };

  STAGE_A(0, 0); STAGE_B(0, 0);
  STAGE_A(1, 1); STAGE_B(1, 1);
  asm volatile("s_waitcnt vmcnt(6)" ::: "memory");
  __builtin_amdgcn_s_barrier();

  int cur = 0, nxt = 1, stg = 2;
  for (int t = 0; t < NT; ++t) {
    const u16* At = As + (size_t)cur * (BM * 64);
    const u16* Bt = Bs + (size_t)cur * (BN * 64);
#pragma unroll
    for (int kk = 0; kk < 2; ++kk) {
      su8v af[4], bf[4];
#pragma unroll
      for (int i = 0; i < 4; ++i)
        af[i] = *(const su8v*)(At + (wm * 64 + i * 16 + l16) * 64 +
                               ((kk * 4 + quad) ^ x7) * 8);
#pragma unroll
      for (int j = 0; j < 4; ++j)
        bf[j] = *(const su8v*)(Bt + (wn * 64 + j * 16 + l16) * 64 +
                               ((kk * 4 + quad) ^ x7) * 8);
      if (t + 2 < NT) {
        if (kk == 0) STAGE_A(t + 2, stg);
        else         STAGE_B(t + 2, stg);
      }
      __builtin_amdgcn_s_setprio(1);
#pragma unroll
      for (int i = 0; i < 4; ++i)
#pragma unroll
        for (int j = 0; j < 4; ++j)
          acc[i][j] = mfma16(af[i], bf[j], acc[i][j]);
      __builtin_amdgcn_s_setprio(0);
    }
    if (t < NT - 2)       asm volatile("s_waitcnt vmcnt(6)" ::: "memory");
    else if (t == NT - 2) asm volatile("s_waitcnt vmcnt(0)" ::: "memory");
    asm volatile("" ::: "memory");
    __builtin_amdgcn_s_barrier();
    asm volatile("" ::: "memory");
    int tmp = cur; cur = nxt; nxt = stg; stg = tmp;
  }
}

// ---------------------------------------------------------------------------
// QKV GEMM: tile = 256 (bn) x 128 (chan). Grid 32x24 = 768 blocks.
// V store: 4-key halves of each 8-key group swapped when (dl&2) (npos^4) so
// attn's bijective Vt granule swizzle (key l16>>1, odd keys allowed) still
// sees key-linear 16B blocks at staging time (see attn_mfma comment).
// ---------------------------------------------------------------------------
__global__ __launch_bounds__(512, 2) void gemm_qkv_mfma(
    const u16* __restrict__ Ax, const u16* __restrict__ weffQ,
    const float* __restrict__ bqkv,
    u16* __restrict__ Qb, u16* __restrict__ Kb, u16* __restrict__ VbT) {
  __shared__ u16 smem[3 * 384 * 64];  // 144 KB: 3-slot ring, A tile + B tile
  int bn0 = blockIdx.x * 256;
  int col0 = blockIdx.y * 128;
  int q = col0 / 768;
  int off = col0 - q * 768;
  int sel = off >> 8;  // 0=Q 1=K 2=V (uniform)
  int head = (q * 256 + (off & 255)) >> 7;
  int tid = threadIdx.x;
  int w = tid >> 6, lane = tid & 63, l16 = lane & 15, quad = lane >> 4;
  f32x4 acc[4][4];
#pragma unroll
  for (int i = 0; i < 4; ++i)
#pragma unroll
    for (int j = 0; j < 4; ++j) acc[i][j] = (f32x4){0.f, 0.f, 0.f, 0.f};

  if (sel == 2) {
    // ---- V: m=bn (256), n=chan (128) ----
    gemm_core8<256, 128>(Ax + (size_t)bn0 * 1024, weffQ + (size_t)col0 * 1024,
                         smem, smem + 3 * 256 * 64, tid, acc);
    int wm = w >> 1, wn = w & 1;
#pragma unroll
    for (int j = 0; j < 4; ++j) {
      int dl = wn * 64 + j * 16 + l16;
      float bias = bqkv[col0 + dl];
      int hswap = (dl & 2) << 1;  // swap 4-key halves when d bit1 set
#pragma unroll
      for (int i = 0; i < 4; ++i) {
        int m = bn0 + wm * 64 + i * 16 + quad * 4;
        int b = m >> 10, npos = m & 1023;
        int bh = b * NHD + head;
        su4v pk;
#pragma unroll
        for (int r = 0; r < 4; ++r) pk[r] = f2b(acc[i][j][r] + bias);
        *(su4v*)(VbT + ((size_t)bh * DD + dl) * NN + (npos ^ hswap)) = pk;
      }
    }
  } else {
    // ---- Q/K: m=chan (128), n=bn (256) ----
    gemm_core8<128, 256>(weffQ + (size_t)col0 * 1024, Ax + (size_t)bn0 * 1024,
                         smem, smem + 3 * 128 * 64, tid, acc);
    int wm = w >> 2, wn = w & 3;
    u16* dst = (sel == 0) ? Qb : Kb;
    float sc = (sel == 0) ? (float)QSC : 1.0f;
#pragma unroll
    for (int i = 0; i < 4; ++i) {
      int dbase = wm * 64 + i * 16 + quad * 4;
      float4 b4 = *(const float4*)(bqkv + col0 + dbase);
#pragma unroll
      for (int j = 0; j < 4; ++j) {
        int n = bn0 + wn * 64 + j * 16 + l16;
        int b = n >> 10, npos = n & 1023;
        int bh = b * NHD + head;
        su4v pk;
        pk[0] = f2b(acc[i][j][0] + b4.x * sc);
        pk[1] = f2b(acc[i][j][1] + b4.y * sc);
        pk[2] = f2b(acc[i][j][2] + b4.z * sc);
        pk[3] = f2b(acc[i][j][3] + b4.w * sc);
        *(su4v*)(dst + ((size_t)bh * NN + npos) * DD + dbase) = pk;
      }
    }
  }
}

// ---------------------------------------------------------------------------
// Flash attention, FULL-K (no split, no merge kernel): 512 blocks =
// qt(8) x bh(64, low bits -> same-bh blocks share XCD for K/V L2 reuse).
// 128 q x 1024 keys per block, KVBLK=32 -> 32 K-tiles, 3-slot LDS ring,
// STAGE(kt+2) at top of kt, counted vmcnt(4) + ONE barrier per tile.
// In-register P (QK^T S^T lane layout == K=16 A-fragment), ones-MFMA rowsum:
// accL[mi][r] = FULL row-sum for exactly the q-rows (quad*4+r) this lane
// owns in accO (same C-layout; all l16 columns equal) -> normalize in-reg
// (inv = 1/accL[r]) and write final AO directly. Removes the OP/LS partial
// round-trip (33.5MB w + 50MB r) and the attn_merge launch.
// Bank layout (conflict-FREE, verified algebraically):
//  - Ks rows 256B = 16 blocks, slot = blk ^ (key&15) (measured 0, round 9).
//  - Vt rows 64B = 8 granules of 4 keys; granule slot = nat ^ (d>>1 & 7):
//    bijective per parity class -> 16-lane phases cover all 32 banks.
//    Odd granule keys break 16B-block atomicity; fixed by storing V
//    globally with 4-key halves swapped when d&2 (gemm_qkv) and staging
//    with block key (dv>>2)&3. slot g holds true granule g^S -> read at
//    (j*4+quad)^S retrieves keys j*16+quad*4..+3 exactly.
// No launch_bounds min-waves (rounds 6/7: caps below natural regs => spill).
// ---------------------------------------------------------------------------
__global__ __launch_bounds__(256) void attn_mfma(
    const u16* __restrict__ Qb, const u16* __restrict__ Kb,
    const u16* __restrict__ VbT, u16* __restrict__ AO) {
  __shared__ u16 Ks[3 * 32 * 128];  // 24 KB ring, 4-bit xor-swizzled blocks
  __shared__ u16 Vt[3 * 128 * 32];  // 24 KB ring, bijective granule swizzle
  int blk = blockIdx.x;
  int bh = blk & 63;
  int qt = blk >> 6;
  int n0 = qt * 128;
  int tid = threadIdx.x;
  int w = tid >> 6, lane = tid & 63, l16 = lane & 15, quad = lane >> 4;
  const u16* Qg = Qb + ((size_t)bh * NN + n0) * DD;
  const u16* Kg = Kb + (size_t)bh * NN * DD;
  const u16* Vg = VbT + (size_t)bh * DD * NN;
  int s7 = l16 >> 1;  // Vt granule swizzle key

  auto STAGE = [&](int kt, int s) {
    int c0 = kt * 32;
#pragma unroll
    for (int t = 0; t < 2; ++t) {
      int ci = w * 2 + t;  // 0..7
      // K: 1KB = 4 rows x 256B; block slot holds global blk^(key&15)
      int krow = ci * 4 + (lane >> 4);
      int kblk = (lane & 15) ^ (krow & 15);
      gll16(Kg + (size_t)(c0 + krow) * DD + kblk * 8, Ks + s * 4096 + ci * 512);
      // V: 1KB = 16 rows x 64B; 16B block slot = nat ^ ((dv>>2)&3); the
      // within-block half order comes pre-swapped from global when dv&2
      int dv = ci * 16 + (lane >> 2);
      int vblk = (lane & 3) ^ ((dv >> 2) & 3);
      gll16(Vg + (size_t)dv * NN + c0 + vblk * 8, Vt + s * 4096 + ci * 512);
    }
  };

  su8v qreg[2][4];  // B-fragment: n=q (l16), k=d
#pragma unroll
  for (int mi = 0; mi < 2; ++mi)
#pragma unroll
    for (int ch = 0; ch < 4; ++ch)
      qreg[mi][ch] = *(const su8v*)(Qg + (size_t)(w * 32 + mi * 16 + l16) * DD +
                                    ch * 32 + quad * 8);

  su4v ones;
  ones[0] = 0x3F80; ones[1] = 0x3F80; ones[2] = 0x3F80; ones[3] = 0x3F80;
  f32x4 accL[2];
  accL[0] = (f32x4){0.f, 0.f, 0.f, 0.f};
  accL[1] = (f32x4){0.f, 0.f, 0.f, 0.f};
  f32x4 accO[2][8];
#pragma unroll
  for (int mi = 0; mi < 2; ++mi)
#pragma unroll
    for (int dt = 0; dt < 8; ++dt) accO[mi][dt] = (f32x4){0.f, 0.f, 0.f, 0.f};

  STAGE(0, 0); STAGE(1, 1);
  asm volatile("s_waitcnt vmcnt(4)" ::: "memory");
  __builtin_amdgcn_s_barrier();

  int cur = 0, nxt = 1, stg = 2;
  for (int kt = 0; kt < 32; ++kt) {
    const u16* Kc = Ks + cur * 4096;
    const u16* Vc = Vt + cur * 4096;
    if (kt + 2 < 32) STAGE(kt + 2, stg);

    // fused per-16-key-slice: QK^T -> exp2/pack -> PV + ones-MFMA row-sum
#pragma unroll
    for (int j = 0; j < 2; ++j) {
      f32x4 s0 = (f32x4){0.f, 0.f, 0.f, 0.f};
      f32x4 s1 = (f32x4){0.f, 0.f, 0.f, 0.f};
#pragma unroll
      for (int ch = 0; ch < 4; ++ch) {
        su8v kf = *(const su8v*)(Kc + (j * 16 + l16) * 128 +
                                 (((ch * 4 + quad) ^ l16) * 8));
        s0 = mfma16(kf, qreg[0][ch], s0);
        s1 = mfma16(kf, qreg[1][ch], s1);
      }
      su4v p0, p1;
#pragma unroll
      for (int r = 0; r < 4; ++r) {
        float pa = __builtin_exp2f(s0[r]);
        p0[r] = (u16)(__builtin_bit_cast(unsigned int, pa) >> 16);
        float pb = __builtin_exp2f(s1[r]);
        p1[r] = (u16)(__builtin_bit_cast(unsigned int, pb) >> 16);
      }
      accL[0] = mfma16h(p0, ones, accL[0]);
      accL[1] = mfma16h(p1, ones, accL[1]);
#pragma unroll
      for (int dt = 0; dt < 8; ++dt) {
        su4v vf = *(const su4v*)(Vc + (dt * 16 + l16) * 32 +
                                 (((j * 4 + quad) ^ s7) * 4));
        accO[0][dt] = mfma16h(p0, vf, accO[0][dt]);
        accO[1][dt] = mfma16h(p1, vf, accO[1][dt]);
      }
    }

    if (kt < 30)       asm volatile("s_waitcnt vmcnt(4)" ::: "memory");
    else if (kt == 30) asm volatile("s_waitcnt vmcnt(0)" ::: "memory");
    if (kt < 31) {
      asm volatile("" ::: "memory");
      __builtin_amdgcn_s_barrier();
      asm volatile("" ::: "memory");
    }
    int tmp = cur; cur = nxt; nxt = stg; stg = tmp;
  }

  // normalize in-register and write final AO[b*1024+n][head*128+d]
  int bb = bh >> 3, head = bh & 7;
#pragma unroll
  for (int mi = 0; mi < 2; ++mi) {
#pragma unroll
    for (int r = 0; r < 4; ++r) {
      int row = w * 32 + mi * 16 + quad * 4 + r;
      float iv = 1.0f / accL[mi][r];
      size_t base = ((size_t)(bb * 1024) + n0 + row) * 1024 + head * 128;
#pragma unroll
      for (int dt = 0; dt < 8; ++dt)
        AO[base + dt * 16 + l16] = f2b(accO[mi][dt][r] * iv);
    }
  }
}

// ---------------------------------------------------------------------------
// quaternion depthwise 3x3 conv (fp32) — writes PE term into workspace
// ---------------------------------------------------------------------------
__global__ __launch_bounds__(256) void qdwconv_kernel(
    const float* __restrict__ x, const float* __restrict__ wpe,
    const float* __restrict__ bpe, float* __restrict__ pe) {
  int blk = blockIdx.x;
  int co = blk & 255;
  int b = blk >> 8;
  __shared__ float pl[4][34 * 34];
  __shared__ float wsm[4][9];
  int tid = threadIdx.x;
  for (int i = tid; i < 4 * 34 * 34; i += 256) ((float*)pl)[i] = 0.f;
  if (tid < 36) wsm[tid / 9][tid % 9] = wpe[((tid / 9) * 256 + co) * 9 + tid % 9];
  __syncthreads();
  for (int i = tid; i < 4 * 1024; i += 256) {
    int p = i >> 10, n = i & 1023;
    int h = n >> 5, ww = n & 31;
    pl[p][(h + 1) * 34 + (ww + 1)] =
        x[(((size_t)b * 256 + co) * 4 + p) * 1024 + n];
  }
  __syncthreads();
  for (int n = tid; n < 1024; n += 256) {
    int h = n >> 5, ww = n & 31;
    float in[4][9];
#pragma unroll
    for (int p = 0; p < 4; ++p)
#pragma unroll
      for (int t = 0; t < 9; ++t)
        in[p][t] = pl[p][(h + t / 3) * 34 + (ww + t % 3)];
#pragma unroll
    for (int q = 0; q < 4; ++q) {
      float acc = bpe[q * 256 + co];
#pragma unroll
      for (int p = 0; p < 4; ++p) {
        int idx = d_IDX[q * 4 + p];
        float s = d_SGN[q * 4 + p];
        float sub = 0.f;
#pragma unroll
        for (int t = 0; t < 9; ++t) sub += in[p][t] * wsm[idx][t];
        acc += s * sub;
      }
      pe[(((size_t)b * 256 + co) * 4 + q) * 1024 + n] = acc;
    }
  }
}

// ---------------------------------------------------------------------------
// proj GEMM: tile = 256 (bn) x 128 (q,o). Grid 32x8 = 256 blocks.
// ---------------------------------------------------------------------------
__global__ __launch_bounds__(512, 2) void gemm_proj_mfma(
    const u16* __restrict__ AO, const u16* __restrict__ weffP,
    const float* __restrict__ bproj, const float* __restrict__ pe,
    float* __restrict__ out) {
  __shared__ u16 smem[3 * 384 * 64];  // 144 KB ring
  int n0 = blockIdx.x * 256;
  int m0 = blockIdx.y * 128;
  int tid = threadIdx.x;
  f32x4 acc[4][4];
#pragma unroll
  for (int i = 0; i < 4; ++i)
#pragma unroll
    for (int j = 0; j < 4; ++j) acc[i][j] = (f32x4){0.f, 0.f, 0.f, 0.f};
  gemm_core8<128, 256>(weffP + (size_t)m0 * 1024, AO + (size_t)n0 * 1024,
                       smem, smem + 3 * 128 * 64, tid, acc);

  int w = tid >> 6, lane = tid & 63, l16 = lane & 15, quad = lane >> 4;
  int wm = w >> 2, wn = w & 3;
#pragma unroll
  for (int i = 0; i < 4; ++i) {
#pragma unroll
    for (int r = 0; r < 4; ++r) {
      int mrow = m0 + wm * 64 + i * 16 + quad * 4 + r;
      int q = mrow >> 8, o = mrow & 255;
      float bias = bproj[mrow];
#pragma unroll
      for (int j = 0; j < 4; ++j) {
        int n = n0 + wn * 64 + j * 16 + l16;
        int b = n >> 10, npos = n & 1023;
        size_t oidx = (((size_t)b * 256 + o) * 4 + q) * 1024 + npos;
        out[oidx] = pe[oidx] + acc[i][j][r] + bias;
      }
    }
  }
}

// ---------------------------------------------------------------------------
extern "C" void kernel_launch(void* const* d_in, const int* in_sizes, int n_in,
                              void* d_out, int out_size, void* d_ws,
                              size_t ws_size, hipStream_t stream) {
  const float* x      = (const float*)d_in[0];
  const float* w_qkv  = (const float*)d_in[1];
  const float* b_qkv  = (const float*)d_in[2];
  const float* w_proj = (const float*)d_in[3];
  const float* b_proj = (const float*)d_in[4];
  const float* w_pe   = (const float*)d_in[5];
  const float* b_pe   = (const float*)d_in[6];
  float* out = (float*)d_out;

  u16* ws = (u16*)d_ws;
  u16* weffQ = ws;                                   // 3072*1024
  u16* weffP = weffQ + (size_t)H3 * DIM;             // 1024*1024
  u16* Ax    = weffP + (size_t)DIM * DIM;            // 8192*1024
  u16* Qb    = Ax + (size_t)MM * DIM;                // 64*1024*128
  u16* Kb    = Qb + (size_t)BB * NHD * NN * DD;      // 64*1024*128
  u16* VbT   = Kb + (size_t)BB * NHD * NN * DD;      // 64*128*1024
  u16* AO    = VbT + (size_t)BB * NHD * DD * NN;     // 8192*1024
  float* PE  = (float*)(AO + (size_t)MM * DIM);      // 8192*1024 fp32
  // (former OP/LS region after PE is now unused)

  hipLaunchKernelGGL(prep_weff, dim3(4096), dim3(256), 0, stream,
                     w_qkv, w_proj, weffQ, weffP);
  hipLaunchKernelGGL(prep_x, dim3(512), dim3(256), 0, stream, x, Ax);
  hipLaunchKernelGGL(gemm_qkv_mfma, dim3(MM / 256, H3 / 128), dim3(512), 0,
                     stream, Ax, weffQ, b_qkv, Qb, Kb, VbT);
  hipLaunchKernelGGL(attn_mfma, dim3(512), dim3(256), 0, stream,
                     Qb, Kb, VbT, AO);
  hipLaunchKernelGGL(qdwconv_kernel, dim3(BB * 256), dim3(256), 0, stream,
                     x, w_pe, b_pe, PE);
  hipLaunchKernelGGL(gemm_proj_mfma, dim3(MM / 256, DIM / 128), dim3(512), 0,
                     stream, AO, weffP, b_proj, PE, out);
}

// Round 12
// 265.930 us; speedup vs baseline: 1.0909x; 1.0258x over previous
//
#include <hip/hip_runtime.h>
#include <hip/hip_bf16.h>

typedef unsigned short u16;
typedef float f32x4 __attribute__((ext_vector_type(4)));
typedef __bf16 bf16x8 __attribute__((ext_vector_type(8)));
typedef __bf16 bf16x4 __attribute__((ext_vector_type(4)));
typedef unsigned short su8v __attribute__((ext_vector_type(8)));
typedef unsigned short su4v __attribute__((ext_vector_type(4)));
typedef short s16x4 __attribute__((ext_vector_type(4)));

#define BB 8
#define NHD 8
#define DD 128
#define NN 1024
#define DIM 1024
#define H3 3072
#define MM 8192
// scale * log2(e), folded into Q weights so softmax is exp2(raw dot)
#define QSC (0.08838834764831845f * 1.4426950408889634f)

__constant__ int   d_IDX[16] = {0,1,2,3, 1,0,3,2, 2,3,0,1, 3,2,1,0};
__constant__ float d_SGN[16] = {1.f,-1.f,-1.f,-1.f, 1.f,1.f,1.f,-1.f,
                                1.f,-1.f,1.f,1.f,  1.f,1.f,-1.f,1.f};

__device__ __forceinline__ f32x4 mfma16(su8v a, su8v b, f32x4 c) {
  return __builtin_amdgcn_mfma_f32_16x16x32_bf16(
      __builtin_bit_cast(bf16x8, a), __builtin_bit_cast(bf16x8, b), c, 0, 0, 0);
}
__device__ __forceinline__ u16 f2b(float f) {  // RNE
  unsigned int u = __builtin_bit_cast(unsigned int, f);
  u += 0x7fffu + ((u >> 16) & 1u);
  return (u16)(u >> 16);
}
__device__ __forceinline__ float b2f(u16 v) {
  unsigned int u = ((unsigned int)v) << 16;
  return __builtin_bit_cast(float, u);
}
typedef const __attribute__((address_space(1))) unsigned int* gas_t;
typedef __attribute__((address_space(3))) unsigned int* las_t;
__device__ __forceinline__ void gll16(const u16* g, u16* l) {
  __builtin_amdgcn_global_load_lds((gas_t)g, (las_t)l, 16, 0, 0);
}

// ---------------------------------------------------------------------------
// prep_weff: effective weights [out_row][in_col] bf16; Q-rows pre-scaled by QSC
// ---------------------------------------------------------------------------
__global__ __launch_bounds__(256) void prep_weff(
    const float* __restrict__ wqkv, const float* __restrict__ wproj,
    u16* __restrict__ weffQ, u16* __restrict__ weffP) {
  int tid = blockIdx.x * 256 + threadIdx.x;
  int stride = gridDim.x * 256;
  for (int i = tid; i < H3 * DIM; i += stride) {
    int row = i >> 10, col = i & 1023;
    int q = row / 768, o = row - q * 768;
    int p = col >> 8, c = col & 255;
    float v = d_SGN[q * 4 + p] * wqkv[(d_IDX[q * 4 + p] * 768 + o) * 256 + c];
    if (o < 256) v *= QSC;  // Q rows
    weffQ[i] = f2b(v);
  }
  for (int i = tid; i < DIM * DIM; i += stride) {
    int row = i >> 10, col = i & 1023;
    int q = row >> 8, o = row & 255;
    int p = col >> 8, c = col & 255;
    weffP[i] = f2b(d_SGN[q * 4 + p] * wproj[(d_IDX[q * 4 + p] * 256 + o) * 256 + c]);
  }
}

// ---------------------------------------------------------------------------
// prep_x: x (B,Cc,4,N) fp32 -> Ax bf16 [8192 (b,n)][1024 (p,c)].
// LDS transpose, layout T[n][pc] stride 264 u16 (16B-aligned su8v reads).
// ---------------------------------------------------------------------------
__global__ __launch_bounds__(256) void prep_x(
    const float* __restrict__ x, u16* __restrict__ Ax) {
  __shared__ u16 T[64 * 264];  // [n][pc], stride 264
  int blk = blockIdx.x;
  int nc = blk & 15;
  int cc = (blk >> 4) & 3;
  int b = blk >> 6;
  int n0 = nc * 64, c0 = cc * 64;
  int tid = threadIdx.x;
  int nseg = tid & 15, rq = tid >> 4;  // rq 0..15
#pragma unroll
  for (int pass = 0; pass < 16; ++pass) {
    int rr = pass * 16 + rq;  // pc local 0..255: p = rr>>6, c = rr&63
    int p = rr >> 6, c = rr & 63;
    float4 f = *(const float4*)(x + (((size_t)(b * 256 + c0 + c)) * 4 + p) * 1024 +
                                n0 + nseg * 4);
    T[(nseg * 4 + 0) * 264 + rr] = f2b(f.x);
    T[(nseg * 4 + 1) * 264 + rr] = f2b(f.y);
    T[(nseg * 4 + 2) * 264 + rr] = f2b(f.z);
    T[(nseg * 4 + 3) * 264 + rr] = f2b(f.w);
  }
  __syncthreads();
  int nl = tid >> 5, lc = tid & 31;
#pragma unroll
  for (int pass = 0; pass < 8; ++pass) {
    int n = pass * 8 + nl;
    su8v v = *(const su8v*)(&T[n * 264 + lc * 8]);
    int pcl = lc * 8;
    *(su8v*)(Ax + (size_t)(b * 1024 + n0 + n) * 1024 + (pcl >> 6) * 256 + c0 +
             (pcl & 63)) = v;
  }
}

// ---------------------------------------------------------------------------
// 8-wave GEMM core, ONE barrier per K-tile + counted vmcnt, free-running
// waves. Tile BM x BN (BM+BN == 384), BK=64, 512 threads = 8 waves of 64x64.
// 3-slot LDS ring; loads for 2 future tiles stay in flight across barriers.
// LDS rows 64 u16 = 8 x 16B blocks, XOR-swizzled (blk ^= row&7); global
// source pre-swizzled identically so gll's linear LDS write lands right.
// ---------------------------------------------------------------------------
template <int BM, int BN>
__device__ __forceinline__ void gemm_core8(
    const u16* __restrict__ Ag, const u16* __restrict__ Bg,
    u16* As, u16* Bs, int tid, f32x4 (&acc)[4][4]) {
  constexpr int WN = BN / 64;
  constexpr int AC = BM / 64;
  constexpr int BC = BN / 64;
  constexpr int NT = 16;  // K = 1024 / BK(64)
  int w = tid >> 6, lane = tid & 63, l16 = lane & 15, quad = lane >> 4;
  int wm = w / WN, wn = w % WN;
  int x7 = l16 & 7;
  int srow = lane >> 3;
  int sblk = (lane & 7) ^ srow;

  auto STAGE_A = [&](int tt, int bs) {
#pragma unroll
    for (int c = 0; c < AC; ++c) {
      int r0 = c * 64 + w * 8;
      gll16(Ag + (size_t)(r0 + srow) * 1024 + tt * 64 + sblk * 8,
            As + (size_t)bs * (BM * 64) + r0 * 64);
    }
  };
  auto STAGE_B = [&](int tt, int bs) {
#pragma unroll
    for (int c = 0; c < BC; ++c) {
      int r0 = c * 64 + w * 8;
      gll16(Bg + (size_t)(r0 + srow) * 1024 + tt * 64 + sblk * 8,
            Bs + (size_t)bs * (BN * 64) + r0 * 64);
    }
  };

  STAGE_A(0, 0); STAGE_B(0, 0);
  STAGE_A(1, 1); STAGE_B(1, 1);
  asm volatile("s_waitcnt vmcnt(6)" ::: "memory");
  __builtin_amdgcn_s_barrier();

  int cur = 0, nxt = 1, stg = 2;
  for (int t = 0; t < NT; ++t) {
    const u16* At = As + (size_t)cur * (BM * 64);
    const u16* Bt = Bs + (size_t)cur * (BN * 64);
#pragma unroll
    for (int kk = 0; kk < 2; ++kk) {
      su8v af[4], bf[4];
#pragma unroll
      for (int i = 0; i < 4; ++i)
        af[i] = *(const su8v*)(At + (wm * 64 + i * 16 + l16) * 64 +
                               ((kk * 4 + quad) ^ x7) * 8);
#pragma unroll
      for (int j = 0; j < 4; ++j)
        bf[j] = *(const su8v*)(Bt + (wn * 64 + j * 16 + l16) * 64 +
                               ((kk * 4 + quad) ^ x7) * 8);
      if (t + 2 < NT) {
        if (kk == 0) STAGE_A(t + 2, stg);
        else         STAGE_B(t + 2, stg);
      }
      __builtin_amdgcn_s_setprio(1);
#pragma unroll
      for (int i = 0; i < 4; ++i)
#pragma unroll
        for (int j = 0; j < 4; ++j)
          acc[i][j] = mfma16(af[i], bf[j], acc[i][j]);
      __builtin_amdgcn_s_setprio(0);
    }
    if (t < NT - 2)       asm volatile("s_waitcnt vmcnt(6)" ::: "memory");
    else if (t == NT - 2) asm volatile("s_waitcnt vmcnt(0)" ::: "memory");
    asm volatile("" ::: "memory");
    __builtin_amdgcn_s_barrier();
    asm volatile("" ::: "memory");
    int tmp = cur; cur = nxt; nxt = stg; stg = tmp;
  }
}

// ---------------------------------------------------------------------------
// QKV GEMM: tile = 256 (bn) x 128 (chan). Grid 32x24 = 768 blocks.
// V store: 4-key halves of each 8-key group swapped when (dl&2) (npos^4) so
// attn's bijective Vt granule swizzle (key l16>>1, odd keys allowed) still
// sees key-linear 16B blocks at staging time (see attn_mfma comment).
// ---------------------------------------------------------------------------
__global__ __launch_bounds__(512, 2) void gemm_qkv_mfma(
    const u16* __restrict__ Ax, const u16* __restrict__ weffQ,
    const float* __restrict__ bqkv,
    u16* __restrict__ Qb, u16* __restrict__ Kb, u16* __restrict__ VbT) {
  __shared__ u16 smem[3 * 384 * 64];  // 144 KB: 3-slot ring, A tile + B tile
  int bn0 = blockIdx.x * 256;
  int col0 = blockIdx.y * 128;
  int q = col0 / 768;
  int off = col0 - q * 768;
  int sel = off >> 8;  // 0=Q 1=K 2=V (uniform)
  int head = (q * 256 + (off & 255)) >> 7;
  int tid = threadIdx.x;
  int w = tid >> 6, lane = tid & 63, l16 = lane & 15, quad = lane >> 4;
  f32x4 acc[4][4];
#pragma unroll
  for (int i = 0; i < 4; ++i)
#pragma unroll
    for (int j = 0; j < 4; ++j) acc[i][j] = (f32x4){0.f, 0.f, 0.f, 0.f};

  if (sel == 2) {
    // ---- V: m=bn (256), n=chan (128) ----
    gemm_core8<256, 128>(Ax + (size_t)bn0 * 1024, weffQ + (size_t)col0 * 1024,
                         smem, smem + 3 * 256 * 64, tid, acc);
    int wm = w >> 1, wn = w & 1;
#pragma unroll
    for (int j = 0; j < 4; ++j) {
      int dl = wn * 64 + j * 16 + l16;
      float bias = bqkv[col0 + dl];
      int hswap = (dl & 2) << 1;  // swap 4-key halves when d bit1 set
#pragma unroll
      for (int i = 0; i < 4; ++i) {
        int m = bn0 + wm * 64 + i * 16 + quad * 4;
        int b = m >> 10, npos = m & 1023;
        int bh = b * NHD + head;
        su4v pk;
#pragma unroll
        for (int r = 0; r < 4; ++r) pk[r] = f2b(acc[i][j][r] + bias);
        *(su4v*)(VbT + ((size_t)bh * DD + dl) * NN + (npos ^ hswap)) = pk;
      }
    }
  } else {
    // ---- Q/K: m=chan (128), n=bn (256) ----
    gemm_core8<128, 256>(weffQ + (size_t)col0 * 1024, Ax + (size_t)bn0 * 1024,
                         smem, smem + 3 * 128 * 64, tid, acc);
    int wm = w >> 2, wn = w & 3;
    u16* dst = (sel == 0) ? Qb : Kb;
    float sc = (sel == 0) ? (float)QSC : 1.0f;
#pragma unroll
    for (int i = 0; i < 4; ++i) {
      int dbase = wm * 64 + i * 16 + quad * 4;
      float4 b4 = *(const float4*)(bqkv + col0 + dbase);
#pragma unroll
      for (int j = 0; j < 4; ++j) {
        int n = bn0 + wn * 64 + j * 16 + l16;
        int b = n >> 10, npos = n & 1023;
        int bh = b * NHD + head;
        su4v pk;
        pk[0] = f2b(acc[i][j][0] + b4.x * sc);
        pk[1] = f2b(acc[i][j][1] + b4.y * sc);
        pk[2] = f2b(acc[i][j][2] + b4.z * sc);
        pk[3] = f2b(acc[i][j][3] + b4.w * sc);
        *(su4v*)(dst + ((size_t)bh * NN + npos) * DD + dbase) = pk;
      }
    }
  }
}

// ---------------------------------------------------------------------------
// Flash attention, FULL-K (no split, no merge kernel): 512 blocks =
// qt(8) x bh(64, low bits -> same-bh blocks share XCD for K/V L2 reuse).
// 128 q x 1024 keys per block, KVBLK=32 -> 32 K-tiles, 3-slot LDS ring,
// STAGE(kt+2) at top of kt, counted vmcnt(4) + ONE barrier per tile.
// In-register P; PV + rowsum at K=32 (round-12): MFMA's k index is only a
// pairing between A and B lanes, so the two 16-key P slices concatenate
// into one K=32 A-fragment {keys quad*4+r (j0), 16+quad*4+r (j1)} and the
// matching V B-fragment is the concat of the same two b64 granule reads
// (addresses unchanged -> conflict-freedom preserved, measured 0).
// Halves PV MFMA issue count vs the legacy 16x16x16 path (52 -> 34
// MFMA/kt): on CDNA4 the K=16 shape is the pre-2xK legacy instruction.
// accL[mi][r] = FULL row-sum for the q-rows this lane owns in accO ->
// normalize in-register, write final AO directly (no OP/LS round trip).
// Bank layout (conflict-free, measured 0 in round 11):
//  - Ks rows 256B = 16 blocks, slot = blk ^ (key&15).
//  - Vt rows 64B = 8 granules of 4 keys; granule slot = nat ^ (l16>>1 key);
//    odd keys need 16B-block atomicity fix: V stored globally with 4-key
//    halves swapped when d&2 (gemm_qkv), staged with block key (dv>>2)&3.
// No launch_bounds min-waves (rounds 6/7: caps below natural regs => spill).
// ---------------------------------------------------------------------------
__global__ __launch_bounds__(256) void attn_mfma(
    const u16* __restrict__ Qb, const u16* __restrict__ Kb,
    const u16* __restrict__ VbT, u16* __restrict__ AO) {
  __shared__ u16 Ks[3 * 32 * 128];  // 24 KB ring, 4-bit xor-swizzled blocks
  __shared__ u16 Vt[3 * 128 * 32];  // 24 KB ring, bijective granule swizzle
  int blk = blockIdx.x;
  int bh = blk & 63;
  int qt = blk >> 6;
  int n0 = qt * 128;
  int tid = threadIdx.x;
  int w = tid >> 6, lane = tid & 63, l16 = lane & 15, quad = lane >> 4;
  const u16* Qg = Qb + ((size_t)bh * NN + n0) * DD;
  const u16* Kg = Kb + (size_t)bh * NN * DD;
  const u16* Vg = VbT + (size_t)bh * DD * NN;
  int s7 = l16 >> 1;  // Vt granule swizzle key

  auto STAGE = [&](int kt, int s) {
    int c0 = kt * 32;
#pragma unroll
    for (int t = 0; t < 2; ++t) {
      int ci = w * 2 + t;  // 0..7
      // K: 1KB = 4 rows x 256B; block slot holds global blk^(key&15)
      int krow = ci * 4 + (lane >> 4);
      int kblk = (lane & 15) ^ (krow & 15);
      gll16(Kg + (size_t)(c0 + krow) * DD + kblk * 8, Ks + s * 4096 + ci * 512);
      // V: 1KB = 16 rows x 64B; 16B block slot = nat ^ ((dv>>2)&3); the
      // within-block half order comes pre-swapped from global when dv&2
      int dv = ci * 16 + (lane >> 2);
      int vblk = (lane & 3) ^ ((dv >> 2) & 3);
      gll16(Vg + (size_t)dv * NN + c0 + vblk * 8, Vt + s * 4096 + ci * 512);
    }
  };

  su8v qreg[2][4];  // B-fragment: n=q (l16), k=d
#pragma unroll
  for (int mi = 0; mi < 2; ++mi)
#pragma unroll
    for (int ch = 0; ch < 4; ++ch)
      qreg[mi][ch] = *(const su8v*)(Qg + (size_t)(w * 32 + mi * 16 + l16) * DD +
                                    ch * 32 + quad * 8);

  su8v ones8;
#pragma unroll
  for (int e = 0; e < 8; ++e) ones8[e] = 0x3F80;
  f32x4 accL[2];
  accL[0] = (f32x4){0.f, 0.f, 0.f, 0.f};
  accL[1] = (f32x4){0.f, 0.f, 0.f, 0.f};
  f32x4 accO[2][8];
#pragma unroll
  for (int mi = 0; mi < 2; ++mi)
#pragma unroll
    for (int dt = 0; dt < 8; ++dt) accO[mi][dt] = (f32x4){0.f, 0.f, 0.f, 0.f};

  STAGE(0, 0); STAGE(1, 1);
  asm volatile("s_waitcnt vmcnt(4)" ::: "memory");
  __builtin_amdgcn_s_barrier();

  int cur = 0, nxt = 1, stg = 2;
  for (int kt = 0; kt < 32; ++kt) {
    const u16* Kc = Ks + cur * 4096;
    const u16* Vc = Vt + cur * 4096;
    if (kt + 2 < 32) STAGE(kt + 2, stg);

    // QK^T for both 16-key slices -> packed P (kept per slice)
    su4v pk[2][2];  // [mi][j]
#pragma unroll
    for (int j = 0; j < 2; ++j) {
      f32x4 s0 = (f32x4){0.f, 0.f, 0.f, 0.f};
      f32x4 s1 = (f32x4){0.f, 0.f, 0.f, 0.f};
#pragma unroll
      for (int ch = 0; ch < 4; ++ch) {
        su8v kf = *(const su8v*)(Kc + (j * 16 + l16) * 128 +
                                 (((ch * 4 + quad) ^ l16) * 8));
        s0 = mfma16(kf, qreg[0][ch], s0);
        s1 = mfma16(kf, qreg[1][ch], s1);
      }
      su4v p0, p1;
#pragma unroll
      for (int r = 0; r < 4; ++r) {
        float pa = __builtin_exp2f(s0[r]);
        p0[r] = (u16)(__builtin_bit_cast(unsigned int, pa) >> 16);
        float pb = __builtin_exp2f(s1[r]);
        p1[r] = (u16)(__builtin_bit_cast(unsigned int, pb) >> 16);
      }
      pk[0][j] = p0;
      pk[1][j] = p1;
    }
    // concat the two slices -> K=32 A-fragments
    su8v p80, p81;
#pragma unroll
    for (int e = 0; e < 4; ++e) {
      p80[e] = pk[0][0][e]; p80[4 + e] = pk[0][1][e];
      p81[e] = pk[1][0][e]; p81[4 + e] = pk[1][1][e];
    }
    accL[0] = mfma16(p80, ones8, accL[0]);
    accL[1] = mfma16(p81, ones8, accL[1]);
    // PV at K=32: B-fragment = concat of the j0/j1 granule reads
#pragma unroll
    for (int dt = 0; dt < 8; ++dt) {
      const u16* vrow = Vc + (dt * 16 + l16) * 32;
      su4v va = *(const su4v*)(vrow + ((quad ^ s7) * 4));
      su4v vb = *(const su4v*)(vrow + (((4 + quad) ^ s7) * 4));
      su8v v8;
#pragma unroll
      for (int e = 0; e < 4; ++e) { v8[e] = va[e]; v8[4 + e] = vb[e]; }
      accO[0][dt] = mfma16(p80, v8, accO[0][dt]);
      accO[1][dt] = mfma16(p81, v8, accO[1][dt]);
    }

    if (kt < 30)       asm volatile("s_waitcnt vmcnt(4)" ::: "memory");
    else if (kt == 30) asm volatile("s_waitcnt vmcnt(0)" ::: "memory");
    if (kt < 31) {
      asm volatile("" ::: "memory");
      __builtin_amdgcn_s_barrier();
      asm volatile("" ::: "memory");
    }
    int tmp = cur; cur = nxt; nxt = stg; stg = tmp;
  }

  // normalize in-register and write final AO[b*1024+n][head*128+d]
  int bb = bh >> 3, head = bh & 7;
#pragma unroll
  for (int mi = 0; mi < 2; ++mi) {
#pragma unroll
    for (int r = 0; r < 4; ++r) {
      int row = w * 32 + mi * 16 + quad * 4 + r;
      float iv = 1.0f / accL[mi][r];
      size_t base = ((size_t)(bb * 1024) + n0 + row) * 1024 + head * 128;
#pragma unroll
      for (int dt = 0; dt < 8; ++dt)
        AO[base + dt * 16 + l16] = f2b(accO[mi][dt][r] * iv);
    }
  }
}

// ---------------------------------------------------------------------------
// quaternion depthwise 3x3 conv (fp32) — writes PE term into workspace
// ---------------------------------------------------------------------------
__global__ __launch_bounds__(256) void qdwconv_kernel(
    const float* __restrict__ x, const float* __restrict__ wpe,
    const float* __restrict__ bpe, float* __restrict__ pe) {
  int blk = blockIdx.x;
  int co = blk & 255;
  int b = blk >> 8;
  __shared__ float pl[4][34 * 34];
  __shared__ float wsm[4][9];
  int tid = threadIdx.x;
  for (int i = tid; i < 4 * 34 * 34; i += 256) ((float*)pl)[i] = 0.f;
  if (tid < 36) wsm[tid / 9][tid % 9] = wpe[((tid / 9) * 256 + co) * 9 + tid % 9];
  __syncthreads();
  for (int i = tid; i < 4 * 1024; i += 256) {
    int p = i >> 10, n = i & 1023;
    int h = n >> 5, ww = n & 31;
    pl[p][(h + 1) * 34 + (ww + 1)] =
        x[(((size_t)b * 256 + co) * 4 + p) * 1024 + n];
  }
  __syncthreads();
  for (int n = tid; n < 1024; n += 256) {
    int h = n >> 5, ww = n & 31;
    float in[4][9];
#pragma unroll
    for (int p = 0; p < 4; ++p)
#pragma unroll
      for (int t = 0; t < 9; ++t)
        in[p][t] = pl[p][(h + t / 3) * 34 + (ww + t % 3)];
#pragma unroll
    for (int q = 0; q < 4; ++q) {
      float acc = bpe[q * 256 + co];
#pragma unroll
      for (int p = 0; p < 4; ++p) {
        int idx = d_IDX[q * 4 + p];
        float s = d_SGN[q * 4 + p];
        float sub = 0.f;
#pragma unroll
        for (int t = 0; t < 9; ++t) sub += in[p][t] * wsm[idx][t];
        acc += s * sub;
      }
      pe[(((size_t)b * 256 + co) * 4 + q) * 1024 + n] = acc;
    }
  }
}

// ---------------------------------------------------------------------------
// proj GEMM: tile = 256 (bn) x 128 (q,o). Grid 32x8 = 256 blocks.
// ---------------------------------------------------------------------------
__global__ __launch_bounds__(512, 2) void gemm_proj_mfma(
    const u16* __restrict__ AO, const u16* __restrict__ weffP,
    const float* __restrict__ bproj, const float* __restrict__ pe,
    float* __restrict__ out) {
  __shared__ u16 smem[3 * 384 * 64];  // 144 KB ring
  int n0 = blockIdx.x * 256;
  int m0 = blockIdx.y * 128;
  int tid = threadIdx.x;
  f32x4 acc[4][4];
#pragma unroll
  for (int i = 0; i < 4; ++i)
#pragma unroll
    for (int j = 0; j < 4; ++j) acc[i][j] = (f32x4){0.f, 0.f, 0.f, 0.f};
  gemm_core8<128, 256>(weffP + (size_t)m0 * 1024, AO + (size_t)n0 * 1024,
                       smem, smem + 3 * 128 * 64, tid, acc);

  int w = tid >> 6, lane = tid & 63, l16 = lane & 15, quad = lane >> 4;
  int wm = w >> 2, wn = w & 3;
#pragma unroll
  for (int i = 0; i < 4; ++i) {
#pragma unroll
    for (int r = 0; r < 4; ++r) {
      int mrow = m0 + wm * 64 + i * 16 + quad * 4 + r;
      int q = mrow >> 8, o = mrow & 255;
      float bias = bproj[mrow];
#pragma unroll
      for (int j = 0; j < 4; ++j) {
        int n = n0 + wn * 64 + j * 16 + l16;
        int b = n >> 10, npos = n & 1023;
        size_t oidx = (((size_t)b * 256 + o) * 4 + q) * 1024 + npos;
        out[oidx] = pe[oidx] + acc[i][j][r] + bias;
      }
    }
  }
}

// ---------------------------------------------------------------------------
extern "C" void kernel_launch(void* const* d_in, const int* in_sizes, int n_in,
                              void* d_out, int out_size, void* d_ws,
                              size_t ws_size, hipStream_t stream) {
  const float* x      = (const float*)d_in[0];
  const float* w_qkv  = (const float*)d_in[1];
  const float* b_qkv  = (const float*)d_in[2];
  const float* w_proj = (const float*)d_in[3];
  const float* b_proj = (const float*)d_in[4];
  const float* w_pe   = (const float*)d_in[5];
  const float* b_pe   = (const float*)d_in[6];
  float* out = (float*)d_out;

  u16* ws = (u16*)d_ws;
  u16* weffQ = ws;                                   // 3072*1024
  u16* weffP = weffQ + (size_t)H3 * DIM;             // 1024*1024
  u16* Ax    = weffP + (size_t)DIM * DIM;            // 8192*1024
  u16* Qb    = Ax + (size_t)MM * DIM;                // 64*1024*128
  u16* Kb    = Qb + (size_t)BB * NHD * NN * DD;      // 64*1024*128
  u16* VbT   = Kb + (size_t)BB * NHD * NN * DD;      // 64*128*1024
  u16* AO    = VbT + (size_t)BB * NHD * DD * NN;     // 8192*1024
  float* PE  = (float*)(AO + (size_t)MM * DIM);      // 8192*1024 fp32
  // (former OP/LS region after PE is now unused)

  hipLaunchKernelGGL(prep_weff, dim3(4096), dim3(256), 0, stream,
                     w_qkv, w_proj, weffQ, weffP);
  hipLaunchKernelGGL(prep_x, dim3(512), dim3(256), 0, stream, x, Ax);
  hipLaunchKernelGGL(gemm_qkv_mfma, dim3(MM / 256, H3 / 128), dim3(512), 0,
                     stream, Ax, weffQ, b_qkv, Qb, Kb, VbT);
  hipLaunchKernelGGL(attn_mfma, dim3(512), dim3(256), 0, stream,
                     Qb, Kb, VbT, AO);
  hipLaunchKernelGGL(qdwconv_kernel, dim3(BB * 256), dim3(256), 0, stream,
                     x, w_pe, b_pe, PE);
  hipLaunchKernelGGL(gemm_proj_mfma, dim3(MM / 256, DIM / 128), dim3(512), 0,
                     stream, AO, weffP, b_proj, PE, out);
}

// Round 13
// 264.891 us; speedup vs baseline: 1.0952x; 1.0039x over previous
//
#include <hip/hip_runtime.h>
#include <hip/hip_bf16.h>

typedef unsigned short u16;
typedef float f32x4 __attribute__((ext_vector_type(4)));
typedef __bf16 bf16x8 __attribute__((ext_vector_type(8)));
typedef __bf16 bf16x4 __attribute__((ext_vector_type(4)));
typedef unsigned short su8v __attribute__((ext_vector_type(8)));
typedef unsigned short su4v __attribute__((ext_vector_type(4)));
typedef short s16x4 __attribute__((ext_vector_type(4)));

#define BB 8
#define NHD 8
#define DD 128
#define NN 1024
#define DIM 1024
#define H3 3072
#define MM 8192
// scale * log2(e), folded into Q weights so softmax is exp2(raw dot)
#define QSC (0.08838834764831845f * 1.4426950408889634f)

__constant__ int   d_IDX[16] = {0,1,2,3, 1,0,3,2, 2,3,0,1, 3,2,1,0};
__constant__ float d_SGN[16] = {1.f,-1.f,-1.f,-1.f, 1.f,1.f,1.f,-1.f,
                                1.f,-1.f,1.f,1.f,  1.f,1.f,-1.f,1.f};

__device__ __forceinline__ f32x4 mfma16(su8v a, su8v b, f32x4 c) {
  return __builtin_amdgcn_mfma_f32_16x16x32_bf16(
      __builtin_bit_cast(bf16x8, a), __builtin_bit_cast(bf16x8, b), c, 0, 0, 0);
}
__device__ __forceinline__ u16 f2b(float f) {  // RNE
  unsigned int u = __builtin_bit_cast(unsigned int, f);
  u += 0x7fffu + ((u >> 16) & 1u);
  return (u16)(u >> 16);
}
__device__ __forceinline__ float b2f(u16 v) {
  unsigned int u = ((unsigned int)v) << 16;
  return __builtin_bit_cast(float, u);
}
typedef const __attribute__((address_space(1))) unsigned int* gas_t;
typedef __attribute__((address_space(3))) unsigned int* las_t;
__device__ __forceinline__ void gll16(const u16* g, u16* l) {
  __builtin_amdgcn_global_load_lds((gas_t)g, (las_t)l, 16, 0, 0);
}

// ---------------------------------------------------------------------------
// prep_weff: effective weights [out_row][in_col] bf16; Q-rows pre-scaled by QSC
// ---------------------------------------------------------------------------
__global__ __launch_bounds__(256) void prep_weff(
    const float* __restrict__ wqkv, const float* __restrict__ wproj,
    u16* __restrict__ weffQ, u16* __restrict__ weffP) {
  int tid = blockIdx.x * 256 + threadIdx.x;
  int stride = gridDim.x * 256;
  for (int i = tid; i < H3 * DIM; i += stride) {
    int row = i >> 10, col = i & 1023;
    int q = row / 768, o = row - q * 768;
    int p = col >> 8, c = col & 255;
    float v = d_SGN[q * 4 + p] * wqkv[(d_IDX[q * 4 + p] * 768 + o) * 256 + c];
    if (o < 256) v *= QSC;  // Q rows
    weffQ[i] = f2b(v);
  }
  for (int i = tid; i < DIM * DIM; i += stride) {
    int row = i >> 10, col = i & 1023;
    int q = row >> 8, o = row & 255;
    int p = col >> 8, c = col & 255;
    weffP[i] = f2b(d_SGN[q * 4 + p] * wproj[(d_IDX[q * 4 + p] * 256 + o) * 256 + c]);
  }
}

// ---------------------------------------------------------------------------
// prep_x: x (B,Cc,4,N) fp32 -> Ax bf16 [8192 (b,n)][1024 (p,c)].
// LDS transpose, layout T[n][pc] stride 264 u16 (16B-aligned su8v reads).
// ---------------------------------------------------------------------------
__global__ __launch_bounds__(256) void prep_x(
    const float* __restrict__ x, u16* __restrict__ Ax) {
  __shared__ u16 T[64 * 264];  // [n][pc], stride 264
  int blk = blockIdx.x;
  int nc = blk & 15;
  int cc = (blk >> 4) & 3;
  int b = blk >> 6;
  int n0 = nc * 64, c0 = cc * 64;
  int tid = threadIdx.x;
  int nseg = tid & 15, rq = tid >> 4;  // rq 0..15
#pragma unroll
  for (int pass = 0; pass < 16; ++pass) {
    int rr = pass * 16 + rq;  // pc local 0..255: p = rr>>6, c = rr&63
    int p = rr >> 6, c = rr & 63;
    float4 f = *(const float4*)(x + (((size_t)(b * 256 + c0 + c)) * 4 + p) * 1024 +
                                n0 + nseg * 4);
    T[(nseg * 4 + 0) * 264 + rr] = f2b(f.x);
    T[(nseg * 4 + 1) * 264 + rr] = f2b(f.y);
    T[(nseg * 4 + 2) * 264 + rr] = f2b(f.z);
    T[(nseg * 4 + 3) * 264 + rr] = f2b(f.w);
  }
  __syncthreads();
  int nl = tid >> 5, lc = tid & 31;
#pragma unroll
  for (int pass = 0; pass < 8; ++pass) {
    int n = pass * 8 + nl;
    su8v v = *(const su8v*)(&T[n * 264 + lc * 8]);
    int pcl = lc * 8;
    *(su8v*)(Ax + (size_t)(b * 1024 + n0 + n) * 1024 + (pcl >> 6) * 256 + c0 +
             (pcl & 63)) = v;
  }
}

// ---------------------------------------------------------------------------
// 8-wave GEMM core, BK=32 (round-13): 3-slot ring = 3*(BM+BN)*32*2B = 72 KB
// -> 2 blocks/CU = 16 waves/CU (was 144 KB -> 1 block, 19% occupancy; the
// 35%-MfmaUtil binder was wave-level overlap, not LDS BW). ONE barrier per
// K-tile + counted vmcnt(3); loads for 2 future tiles in flight across
// barriers; 3 gll/wave/tile for both instantiations (static_assert).
// LDS rows 32 u16 = 4 x 16B blocks; swizzle key (row>>1)&3: write slot
// (lane&3)^((srow>>1)&3), read slot quad^((l16>>1)&3). Bank check (b128,
// 16-lane phases, 64B rows): bank_start = (16*l16 + 4*(quad^((l16>>1)&3)))
// %32 -> 8 distinct starts x 2 lanes = 2-way everywhere (free).
// ---------------------------------------------------------------------------
template <int BM, int BN>
__device__ __forceinline__ void gemm_core8(
    const u16* __restrict__ Ag, const u16* __restrict__ Bg,
    u16* As, u16* Bs, int tid, f32x4 (&acc)[4][4]) {
  constexpr int WN = BN / 64;
  constexpr int AC = BM / 128;  // gll per wave for A tile (16 rows each)
  constexpr int BC = BN / 128;
  constexpr int NT = 32;        // K = 1024 / BK(32)
  static_assert(AC + BC == 3, "vmcnt(3) assumes 3 gll per wave per tile");
  int w = tid >> 6, lane = tid & 63, l16 = lane & 15, quad = lane >> 4;
  int wm = w / WN, wn = w % WN;
  int sx = (l16 >> 1) & 3;            // fragment-read swizzle key
  int srow = lane >> 2;               // 0..15 within staged 16-row group
  int sblk = (lane & 3) ^ ((srow >> 1) & 3);

  auto STAGE_A = [&](int tt, int bs) {
#pragma unroll
    for (int c = 0; c < AC; ++c) {
      int r0 = (c * 8 + w) * 16;      // wave-uniform row base
      gll16(Ag + (size_t)(r0 + srow) * 1024 + tt * 32 + sblk * 8,
            As + (size_t)bs * (BM * 32) + r0 * 32);
    }
  };
  auto STAGE_B = [&](int tt, int bs) {
#pragma unroll
    for (int c = 0; c < BC; ++c) {
      int r0 = (c * 8 + w) * 16;
      gll16(Bg + (size_t)(r0 + srow) * 1024 + tt * 32 + sblk * 8,
            Bs + (size_t)bs * (BN * 32) + r0 * 32);
    }
  };

  STAGE_A(0, 0); STAGE_B(0, 0);
  STAGE_A(1, 1); STAGE_B(1, 1);
  asm volatile("s_waitcnt vmcnt(3)" ::: "memory");
  __builtin_amdgcn_s_barrier();

  int cur = 0, nxt = 1, stg = 2;
  for (int t = 0; t < NT; ++t) {
    const u16* At = As + (size_t)cur * (BM * 32);
    const u16* Bt = Bs + (size_t)cur * (BN * 32);
    su8v af[4], bf[4];
#pragma unroll
    for (int i = 0; i < 4; ++i)
      af[i] = *(const su8v*)(At + (wm * 64 + i * 16 + l16) * 32 +
                             ((quad ^ sx) * 8));
#pragma unroll
    for (int j = 0; j < 4; ++j)
      bf[j] = *(const su8v*)(Bt + (wn * 64 + j * 16 + l16) * 32 +
                             ((quad ^ sx) * 8));
    if (t + 2 < NT) {
      STAGE_A(t + 2, stg);
      STAGE_B(t + 2, stg);
    }
    __builtin_amdgcn_s_setprio(1);
#pragma unroll
    for (int i = 0; i < 4; ++i)
#pragma unroll
      for (int j = 0; j < 4; ++j)
        acc[i][j] = mfma16(af[i], bf[j], acc[i][j]);
    __builtin_amdgcn_s_setprio(0);
    if (t < NT - 2)       asm volatile("s_waitcnt vmcnt(3)" ::: "memory");
    else if (t == NT - 2) asm volatile("s_waitcnt vmcnt(0)" ::: "memory");
    if (t < NT - 1) {
      asm volatile("" ::: "memory");
      __builtin_amdgcn_s_barrier();
      asm volatile("" ::: "memory");
    }
    int tmp = cur; cur = nxt; nxt = stg; stg = tmp;
  }
}

// ---------------------------------------------------------------------------
// QKV GEMM: tile = 256 (bn) x 128 (chan). Grid 32x24 = 768 blocks.
// V store: 4-key halves of each 8-key group swapped when (dl&2) (npos^4) so
// attn's bijective Vt granule swizzle (key l16>>1, odd keys allowed) still
// sees key-linear 16B blocks at staging time (see attn_mfma comment).
// ---------------------------------------------------------------------------
__global__ __launch_bounds__(512, 2) void gemm_qkv_mfma(
    const u16* __restrict__ Ax, const u16* __restrict__ weffQ,
    const float* __restrict__ bqkv,
    u16* __restrict__ Qb, u16* __restrict__ Kb, u16* __restrict__ VbT) {
  __shared__ u16 smem[3 * 384 * 32];  // 72 KB: 3-slot ring, A tile + B tile
  int bn0 = blockIdx.x * 256;
  int col0 = blockIdx.y * 128;
  int q = col0 / 768;
  int off = col0 - q * 768;
  int sel = off >> 8;  // 0=Q 1=K 2=V (uniform)
  int head = (q * 256 + (off & 255)) >> 7;
  int tid = threadIdx.x;
  int w = tid >> 6, lane = tid & 63, l16 = lane & 15, quad = lane >> 4;
  f32x4 acc[4][4];
#pragma unroll
  for (int i = 0; i < 4; ++i)
#pragma unroll
    for (int j = 0; j < 4; ++j) acc[i][j] = (f32x4){0.f, 0.f, 0.f, 0.f};

  if (sel == 2) {
    // ---- V: m=bn (256), n=chan (128) ----
    gemm_core8<256, 128>(Ax + (size_t)bn0 * 1024, weffQ + (size_t)col0 * 1024,
                         smem, smem + 3 * 256 * 32, tid, acc);
    int wm = w >> 1, wn = w & 1;
#pragma unroll
    for (int j = 0; j < 4; ++j) {
      int dl = wn * 64 + j * 16 + l16;
      float bias = bqkv[col0 + dl];
      int hswap = (dl & 2) << 1;  // swap 4-key halves when d bit1 set
#pragma unroll
      for (int i = 0; i < 4; ++i) {
        int m = bn0 + wm * 64 + i * 16 + quad * 4;
        int b = m >> 10, npos = m & 1023;
        int bh = b * NHD + head;
        su4v pk;
#pragma unroll
        for (int r = 0; r < 4; ++r) pk[r] = f2b(acc[i][j][r] + bias);
        *(su4v*)(VbT + ((size_t)bh * DD + dl) * NN + (npos ^ hswap)) = pk;
      }
    }
  } else {
    // ---- Q/K: m=chan (128), n=bn (256) ----
    gemm_core8<128, 256>(weffQ + (size_t)col0 * 1024, Ax + (size_t)bn0 * 1024,
                         smem, smem + 3 * 128 * 32, tid, acc);
    int wm = w >> 2, wn = w & 3;
    u16* dst = (sel == 0) ? Qb : Kb;
    float sc = (sel == 0) ? (float)QSC : 1.0f;
#pragma unroll
    for (int i = 0; i < 4; ++i) {
      int dbase = wm * 64 + i * 16 + quad * 4;
      float4 b4 = *(const float4*)(bqkv + col0 + dbase);
#pragma unroll
      for (int j = 0; j < 4; ++j) {
        int n = bn0 + wn * 64 + j * 16 + l16;
        int b = n >> 10, npos = n & 1023;
        int bh = b * NHD + head;
        su4v pk;
        pk[0] = f2b(acc[i][j][0] + b4.x * sc);
        pk[1] = f2b(acc[i][j][1] + b4.y * sc);
        pk[2] = f2b(acc[i][j][2] + b4.z * sc);
        pk[3] = f2b(acc[i][j][3] + b4.w * sc);
        *(su4v*)(dst + ((size_t)bh * NN + npos) * DD + dbase) = pk;
      }
    }
  }
}

// ---------------------------------------------------------------------------
// Flash attention, FULL-K (no split, no merge kernel): 512 blocks =
// qt(8) x bh(64, low bits -> same-bh blocks share XCD for K/V L2 reuse).
// 128 q x 1024 keys per block, KVBLK=32 -> 32 K-tiles, 3-slot LDS ring,
// STAGE(kt+2) at top of kt, counted vmcnt(4) + ONE barrier per tile.
// In-register P; PV + rowsum at K=32: the two 16-key P slices concatenate
// into one K=32 A-fragment and the matching V B-fragment is the concat of
// the same two b64 granule reads (round 12: halved PV MFMA issue count).
// accL[mi][r] = FULL row-sum for the q-rows this lane owns in accO ->
// normalize in-register, write final AO directly (no OP/LS round trip).
// Bank layout (conflict-free, measured 0 in rounds 11/12):
//  - Ks rows 256B = 16 blocks, slot = blk ^ (key&15).
//  - Vt rows 64B = 8 granules of 4 keys; granule slot = nat ^ (l16>>1 key);
//    odd keys need 16B-block atomicity fix: V stored globally with 4-key
//    halves swapped when d&2 (gemm_qkv), staged with block key (dv>>2)&3.
// No launch_bounds min-waves (rounds 6/7: caps below natural regs => spill).
// ---------------------------------------------------------------------------
__global__ __launch_bounds__(256) void attn_mfma(
    const u16* __restrict__ Qb, const u16* __restrict__ Kb,
    const u16* __restrict__ VbT, u16* __restrict__ AO) {
  __shared__ u16 Ks[3 * 32 * 128];  // 24 KB ring, 4-bit xor-swizzled blocks
  __shared__ u16 Vt[3 * 128 * 32];  // 24 KB ring, bijective granule swizzle
  int blk = blockIdx.x;
  int bh = blk & 63;
  int qt = blk >> 6;
  int n0 = qt * 128;
  int tid = threadIdx.x;
  int w = tid >> 6, lane = tid & 63, l16 = lane & 15, quad = lane >> 4;
  const u16* Qg = Qb + ((size_t)bh * NN + n0) * DD;
  const u16* Kg = Kb + (size_t)bh * NN * DD;
  const u16* Vg = VbT + (size_t)bh * DD * NN;
  int s7 = l16 >> 1;  // Vt granule swizzle key

  auto STAGE = [&](int kt, int s) {
    int c0 = kt * 32;
#pragma unroll
    for (int t = 0; t < 2; ++t) {
      int ci = w * 2 + t;  // 0..7
      // K: 1KB = 4 rows x 256B; block slot holds global blk^(key&15)
      int krow = ci * 4 + (lane >> 4);
      int kblk = (lane & 15) ^ (krow & 15);
      gll16(Kg + (size_t)(c0 + krow) * DD + kblk * 8, Ks + s * 4096 + ci * 512);
      // V: 1KB = 16 rows x 64B; 16B block slot = nat ^ ((dv>>2)&3); the
      // within-block half order comes pre-swapped from global when dv&2
      int dv = ci * 16 + (lane >> 2);
      int vblk = (lane & 3) ^ ((dv >> 2) & 3);
      gll16(Vg + (size_t)dv * NN + c0 + vblk * 8, Vt + s * 4096 + ci * 512);
    }
  };

  su8v qreg[2][4];  // B-fragment: n=q (l16), k=d
#pragma unroll
  for (int mi = 0; mi < 2; ++mi)
#pragma unroll
    for (int ch = 0; ch < 4; ++ch)
      qreg[mi][ch] = *(const su8v*)(Qg + (size_t)(w * 32 + mi * 16 + l16) * DD +
                                    ch * 32 + quad * 8);

  su8v ones8;
#pragma unroll
  for (int e = 0; e < 8; ++e) ones8[e] = 0x3F80;
  f32x4 accL[2];
  accL[0] = (f32x4){0.f, 0.f, 0.f, 0.f};
  accL[1] = (f32x4){0.f, 0.f, 0.f, 0.f};
  f32x4 accO[2][8];
#pragma unroll
  for (int mi = 0; mi < 2; ++mi)
#pragma unroll
    for (int dt = 0; dt < 8; ++dt) accO[mi][dt] = (f32x4){0.f, 0.f, 0.f, 0.f};

  STAGE(0, 0); STAGE(1, 1);
  asm volatile("s_waitcnt vmcnt(4)" ::: "memory");
  __builtin_amdgcn_s_barrier();

  int cur = 0, nxt = 1, stg = 2;
  for (int kt = 0; kt < 32; ++kt) {
    const u16* Kc = Ks + cur * 4096;
    const u16* Vc = Vt + cur * 4096;
    if (kt + 2 < 32) STAGE(kt + 2, stg);

    // QK^T for both 16-key slices -> packed P (kept per slice)
    su4v pk[2][2];  // [mi][j]
#pragma unroll
    for (int j = 0; j < 2; ++j) {
      f32x4 s0 = (f32x4){0.f, 0.f, 0.f, 0.f};
      f32x4 s1 = (f32x4){0.f, 0.f, 0.f, 0.f};
#pragma unroll
      for (int ch = 0; ch < 4; ++ch) {
        su8v kf = *(const su8v*)(Kc + (j * 16 + l16) * 128 +
                                 (((ch * 4 + quad) ^ l16) * 8));
        s0 = mfma16(kf, qreg[0][ch], s0);
        s1 = mfma16(kf, qreg[1][ch], s1);
      }
      su4v p0, p1;
#pragma unroll
      for (int r = 0; r < 4; ++r) {
        float pa = __builtin_exp2f(s0[r]);
        p0[r] = (u16)(__builtin_bit_cast(unsigned int, pa) >> 16);
        float pb = __builtin_exp2f(s1[r]);
        p1[r] = (u16)(__builtin_bit_cast(unsigned int, pb) >> 16);
      }
      pk[0][j] = p0;
      pk[1][j] = p1;
    }
    // concat the two slices -> K=32 A-fragments
    su8v p80, p81;
#pragma unroll
    for (int e = 0; e < 4; ++e) {
      p80[e] = pk[0][0][e]; p80[4 + e] = pk[0][1][e];
      p81[e] = pk[1][0][e]; p81[4 + e] = pk[1][1][e];
    }
    accL[0] = mfma16(p80, ones8, accL[0]);
    accL[1] = mfma16(p81, ones8, accL[1]);
    // PV at K=32: B-fragment = concat of the j0/j1 granule reads
#pragma unroll
    for (int dt = 0; dt < 8; ++dt) {
      const u16* vrow = Vc + (dt * 16 + l16) * 32;
      su4v va = *(const su4v*)(vrow + ((quad ^ s7) * 4));
      su4v vb = *(const su4v*)(vrow + (((4 + quad) ^ s7) * 4));
      su8v v8;
#pragma unroll
      for (int e = 0; e < 4; ++e) { v8[e] = va[e]; v8[4 + e] = vb[e]; }
      accO[0][dt] = mfma16(p80, v8, accO[0][dt]);
      accO[1][dt] = mfma16(p81, v8, accO[1][dt]);
    }

    if (kt < 30)       asm volatile("s_waitcnt vmcnt(4)" ::: "memory");
    else if (kt == 30) asm volatile("s_waitcnt vmcnt(0)" ::: "memory");
    if (kt < 31) {
      asm volatile("" ::: "memory");
      __builtin_amdgcn_s_barrier();
      asm volatile("" ::: "memory");
    }
    int tmp = cur; cur = nxt; nxt = stg; stg = tmp;
  }

  // normalize in-register and write final AO[b*1024+n][head*128+d]
  int bb = bh >> 3, head = bh & 7;
#pragma unroll
  for (int mi = 0; mi < 2; ++mi) {
#pragma unroll
    for (int r = 0; r < 4; ++r) {
      int row = w * 32 + mi * 16 + quad * 4 + r;
      float iv = 1.0f / accL[mi][r];
      size_t base = ((size_t)(bb * 1024) + n0 + row) * 1024 + head * 128;
#pragma unroll
      for (int dt = 0; dt < 8; ++dt)
        AO[base + dt * 16 + l16] = f2b(accO[mi][dt][r] * iv);
    }
  }
}

// ---------------------------------------------------------------------------
// quaternion depthwise 3x3 conv (fp32) — writes PE term into workspace
// ---------------------------------------------------------------------------
__global__ __launch_bounds__(256) void qdwconv_kernel(
    const float* __restrict__ x, const float* __restrict__ wpe,
    const float* __restrict__ bpe, float* __restrict__ pe) {
  int blk = blockIdx.x;
  int co = blk & 255;
  int b = blk >> 8;
  __shared__ float pl[4][34 * 34];
  __shared__ float wsm[4][9];
  int tid = threadIdx.x;
  for (int i = tid; i < 4 * 34 * 34; i += 256) ((float*)pl)[i] = 0.f;
  if (tid < 36) wsm[tid / 9][tid % 9] = wpe[((tid / 9) * 256 + co) * 9 + tid % 9];
  __syncthreads();
  for (int i = tid; i < 4 * 1024; i += 256) {
    int p = i >> 10, n = i & 1023;
    int h = n >> 5, ww = n & 31;
    pl[p][(h + 1) * 34 + (ww + 1)] =
        x[(((size_t)b * 256 + co) * 4 + p) * 1024 + n];
  }
  __syncthreads();
  for (int n = tid; n < 1024; n += 256) {
    int h = n >> 5, ww = n & 31;
    float in[4][9];
#pragma unroll
    for (int p = 0; p < 4; ++p)
#pragma unroll
      for (int t = 0; t < 9; ++t)
        in[p][t] = pl[p][(h + t / 3) * 34 + (ww + t % 3)];
#pragma unroll
    for (int q = 0; q < 4; ++q) {
      float acc = bpe[q * 256 + co];
#pragma unroll
      for (int p = 0; p < 4; ++p) {
        int idx = d_IDX[q * 4 + p];
        float s = d_SGN[q * 4 + p];
        float sub = 0.f;
#pragma unroll
        for (int t = 0; t < 9; ++t) sub += in[p][t] * wsm[idx][t];
        acc += s * sub;
      }
      pe[(((size_t)b * 256 + co) * 4 + q) * 1024 + n] = acc;
    }
  }
}

// ---------------------------------------------------------------------------
// proj GEMM: tile = 256 (bn) x 128 (q,o). Grid 32x8 = 256 blocks.
// ---------------------------------------------------------------------------
__global__ __launch_bounds__(512, 2) void gemm_proj_mfma(
    const u16* __restrict__ AO, const u16* __restrict__ weffP,
    const float* __restrict__ bproj, const float* __restrict__ pe,
    float* __restrict__ out) {
  __shared__ u16 smem[3 * 384 * 32];  // 72 KB ring
  int n0 = blockIdx.x * 256;
  int m0 = blockIdx.y * 128;
  int tid = threadIdx.x;
  f32x4 acc[4][4];
#pragma unroll
  for (int i = 0; i < 4; ++i)
#pragma unroll
    for (int j = 0; j < 4; ++j) acc[i][j] = (f32x4){0.f, 0.f, 0.f, 0.f};
  gemm_core8<128, 256>(weffP + (size_t)m0 * 1024, AO + (size_t)n0 * 1024,
                       smem, smem + 3 * 128 * 32, tid, acc);

  int w = tid >> 6, lane = tid & 63, l16 = lane & 15, quad = lane >> 4;
  int wm = w >> 2, wn = w & 3;
#pragma unroll
  for (int i = 0; i < 4; ++i) {
#pragma unroll
    for (int r = 0; r < 4; ++r) {
      int mrow = m0 + wm * 64 + i * 16 + quad * 4 + r;
      int q = mrow >> 8, o = mrow & 255;
      float bias = bproj[mrow];
#pragma unroll
      for (int j = 0; j < 4; ++j) {
        int n = n0 + wn * 64 + j * 16 + l16;
        int b = n >> 10, npos = n & 1023;
        size_t oidx = (((size_t)b * 256 + o) * 4 + q) * 1024 + npos;
        out[oidx] = pe[oidx] + acc[i][j][r] + bias;
      }
    }
  }
}

// ---------------------------------------------------------------------------
extern "C" void kernel_launch(void* const* d_in, const int* in_sizes, int n_in,
                              void* d_out, int out_size, void* d_ws,
                              size_t ws_size, hipStream_t stream) {
  const float* x      = (const float*)d_in[0];
  const float* w_qkv  = (const float*)d_in[1];
  const float* b_qkv  = (const float*)d_in[2];
  const float* w_proj = (const float*)d_in[3];
  const float* b_proj = (const float*)d_in[4];
  const float* w_pe   = (const float*)d_in[5];
  const float* b_pe   = (const float*)d_in[6];
  float* out = (float*)d_out;

  u16* ws = (u16*)d_ws;
  u16* weffQ = ws;                                   // 3072*1024
  u16* weffP = weffQ + (size_t)H3 * DIM;             // 1024*1024
  u16* Ax    = weffP + (size_t)DIM * DIM;            // 8192*1024
  u16* Qb    = Ax + (size_t)MM * DIM;                // 64*1024*128
  u16* Kb    = Qb + (size_t)BB * NHD * NN * DD;      // 64*1024*128
  u16* VbT   = Kb + (size_t)BB * NHD * NN * DD;      // 64*128*1024
  u16* AO    = VbT + (size_t)BB * NHD * DD * NN;     // 8192*1024
  float* PE  = (float*)(AO + (size_t)MM * DIM);      // 8192*1024 fp32
  // (former OP/LS region after PE is now unused)

  hipLaunchKernelGGL(prep_weff, dim3(4096), dim3(256), 0, stream,
                     w_qkv, w_proj, weffQ, weffP);
  hipLaunchKernelGGL(prep_x, dim3(512), dim3(256), 0, stream, x, Ax);
  hipLaunchKernelGGL(gemm_qkv_mfma, dim3(MM / 256, H3 / 128), dim3(512), 0,
                     stream, Ax, weffQ, b_qkv, Qb, Kb, VbT);
  hipLaunchKernelGGL(attn_mfma, dim3(512), dim3(256), 0, stream,
                     Qb, Kb, VbT, AO);
  hipLaunchKernelGGL(qdwconv_kernel, dim3(BB * 256), dim3(256), 0, stream,
                     x, w_pe, b_pe, PE);
  hipLaunchKernelGGL(gemm_proj_mfma, dim3(MM / 256, DIM / 128), dim3(512), 0,
                     stream, AO, weffP, b_proj, PE, out);
}